// Round 1
// baseline (1600.641 us; speedup 1.0000x reference)
//
#include <hip/hip_runtime.h>
#include <math.h>

#define D_MODEL 1024
#define D_STATE 16
#define D_CONV  4
#define D_INNER 2048
#define LSEQ    1024
#define BATCH   2
#define NROWS   (BATCH * LSEQ)       // 2048
#define EPSV    1e-6f

__device__ __forceinline__ float silu_f(float x) { return x / (1.0f + expf(-x)); }

// ---------------- RMSNorm: one block per row of 1024 ----------------
__global__ __launch_bounds__(256) void rmsnorm_kernel(const float* __restrict__ x,
                                                      const float* __restrict__ w,
                                                      float* __restrict__ xn) {
    int row = blockIdx.x;
    const float4* xr = (const float4*)(x + (size_t)row * D_MODEL);
    float4 v = xr[threadIdx.x];                       // 256 threads * 4 = 1024
    float s = v.x * v.x + v.y * v.y + v.z * v.z + v.w * v.w;
#pragma unroll
    for (int off = 32; off > 0; off >>= 1) s += __shfl_down(s, off, 64);
    __shared__ float wsum[4];
    int lane = threadIdx.x & 63, wv = threadIdx.x >> 6;
    if (lane == 0) wsum[wv] = s;
    __syncthreads();
    float tot = wsum[0] + wsum[1] + wsum[2] + wsum[3];
    float scale = rsqrtf(tot * (1.0f / D_MODEL) + EPSV);
    const float4* wr = (const float4*)w;
    float4 wv4 = wr[threadIdx.x];
    float4 o;
    o.x = v.x * scale * wv4.x;
    o.y = v.y * scale * wv4.y;
    o.z = v.z * scale * wv4.z;
    o.w = v.w * scale * wv4.w;
    ((float4*)(xn + (size_t)row * D_MODEL))[threadIdx.x] = o;
}

// ---------------- GEMM NT: C[m,n] = sum_k A[m,k]*B[n,k] (+resid) ----------------
// BM=BN=64, BK=32, 256 threads, 4x4 micro-tile, transposed LDS tiles.
__global__ __launch_bounds__(256) void gemm_nt64(const float* __restrict__ A,
                                                 const float* __restrict__ Bm,
                                                 float* __restrict__ C,
                                                 const float* __restrict__ resid,
                                                 int M, int N, int K) {
    const int BM = 64, BN = 64, BK = 32;
    __shared__ float As[BK][BM];
    __shared__ float Bs[BK][BN];
    int tid = threadIdx.x;
    int tx = tid & 15, ty = tid >> 4;
    int m0 = blockIdx.y * BM, n0 = blockIdx.x * BN;
    float acc[4][4] = {};
    for (int k0 = 0; k0 < K; k0 += BK) {
#pragma unroll
        for (int it = 0; it < 2; ++it) {
            int f = tid + it * 256;
            int row = f >> 3;          // 0..63
            int kc = (f & 7) * 4;      // 0,4,...,28
            float4 va = *(const float4*)(A + (size_t)(m0 + row) * K + k0 + kc);
            As[kc + 0][row] = va.x; As[kc + 1][row] = va.y;
            As[kc + 2][row] = va.z; As[kc + 3][row] = va.w;
            float4 vb = *(const float4*)(Bm + (size_t)(n0 + row) * K + k0 + kc);
            Bs[kc + 0][row] = vb.x; Bs[kc + 1][row] = vb.y;
            Bs[kc + 2][row] = vb.z; Bs[kc + 3][row] = vb.w;
        }
        __syncthreads();
#pragma unroll
        for (int kk = 0; kk < BK; kk++) {
            float4 a4 = *(const float4*)&As[kk][ty * 4];
            float4 b4 = *(const float4*)&Bs[kk][tx * 4];
            float a[4] = {a4.x, a4.y, a4.z, a4.w};
            float b[4] = {b4.x, b4.y, b4.z, b4.w};
#pragma unroll
            for (int i = 0; i < 4; i++)
#pragma unroll
                for (int j = 0; j < 4; j++) acc[i][j] += a[i] * b[j];
        }
        __syncthreads();
    }
#pragma unroll
    for (int i = 0; i < 4; i++) {
        int m = m0 + ty * 4 + i;
        int n = n0 + tx * 4;
        float4 o = {acc[i][0], acc[i][1], acc[i][2], acc[i][3]};
        if (resid) {
            float4 r = *(const float4*)(resid + (size_t)m * N + n);
            o.x += r.x; o.y += r.y; o.z += r.z; o.w += r.w;
        }
        *(float4*)(C + (size_t)m * N + n) = o;
    }
}

// ---------------- depthwise causal conv(4) + bias + SiLU ----------------
// x_ssm[b,l,d] = xz[b,l,d] (first half); out[b,l,d] = silu(b[d] + sum_j w[d,j]*x[b,l-3+j,d])
__global__ __launch_bounds__(256) void conv_silu_kernel(const float* __restrict__ xz,
                                                        const float* __restrict__ w,
                                                        const float* __restrict__ cb,
                                                        float* __restrict__ xc) {
    int idx = blockIdx.x * 256 + threadIdx.x;     // B*L*D_INNER
    int d = idx & (D_INNER - 1);
    int bl = idx >> 11;
    int l = bl & (LSEQ - 1);
    int bb = bl >> 10;
    float w0 = w[d * 4 + 0], w1 = w[d * 4 + 1], w2 = w[d * 4 + 2], w3 = w[d * 4 + 3];
    const float* base = xz + (size_t)(bb * LSEQ) * (2 * D_INNER) + d;
    float acc = cb[d];
    if (l >= 3) acc += w0 * base[(size_t)(l - 3) * (2 * D_INNER)];
    if (l >= 2) acc += w1 * base[(size_t)(l - 2) * (2 * D_INNER)];
    if (l >= 1) acc += w2 * base[(size_t)(l - 1) * (2 * D_INNER)];
    acc += w3 * base[(size_t)l * (2 * D_INNER)];
    xc[idx] = silu_f(acc);
}

// ---------------- ssm_params = xc @ W_x^T  (N=33) ----------------
__global__ __launch_bounds__(256) void params_kernel(const float* __restrict__ xc,
                                                     const float* __restrict__ Wx,
                                                     float* __restrict__ ssm) {
    int row = blockIdx.x;   // B*L
    __shared__ float xs[D_INNER];
    const float4* xr = (const float4*)(xc + (size_t)row * D_INNER);
#pragma unroll
    for (int it = 0; it < 2; it++) {
        int f = threadIdx.x + it * 256;
        float4 v = xr[f];
        *(float4*)&xs[f * 4] = v;
    }
    __syncthreads();
    int lane = threadIdx.x & 63;
    int wv = threadIdx.x >> 6;
    for (int n = wv; n < 2 * D_STATE + 1; n += 4) {
        const float* wrow = Wx + (size_t)n * D_INNER;
        float s = 0.0f;
        for (int k = lane; k < D_INNER; k += 64) s += xs[k] * wrow[k];
#pragma unroll
        for (int off = 32; off > 0; off >>= 1) s += __shfl_down(s, off, 64);
        if (lane == 0) ssm[(size_t)row * 33 + n] = s;
    }
}

// ---------------- selective scan (state-parallel, 16 lanes/channel) ----------------
// block = 256 threads = 16 channels x 16 states; grid = B * (D_INNER/16) = 256
__global__ __launch_bounds__(256) void scan_kernel(const float* __restrict__ ssm,
                                                   const float* __restrict__ xc,
                                                   const float* __restrict__ xz,
                                                   const float* __restrict__ A_log,
                                                   const float* __restrict__ Dskip,
                                                   const float* __restrict__ Wdt,
                                                   const float* __restrict__ bdt,
                                                   float* __restrict__ y) {
    int bi = blockIdx.x;
    int bb = bi >> 7;
    int dbase = (bi & 127) * 16;
    int n = threadIdx.x & 15;
    int ch = threadIdx.x >> 4;
    int d = dbase + ch;
    float Adn = -expf(A_log[(size_t)d * D_STATE + n]);
    float wdt = Wdt[d], bdtv = bdt[d], dsk = Dskip[d];
    float h = 0.0f;
    const float* srow = ssm + (size_t)bb * LSEQ * 33;
    const float* xrow = xc + (size_t)bb * LSEQ * D_INNER + d;
    const float* zrow = xz + (size_t)bb * LSEQ * (2 * D_INNER) + D_INNER + d;
    float* yrow = y + (size_t)bb * LSEQ * D_INNER + d;
    for (int t = 0; t < LSEQ; t++) {
        const float* sp = srow + t * 33;
        float Bn = sp[n];
        float Cn = sp[16 + n];
        float dtr = sp[32];
        float xt = xrow[(size_t)t * D_INNER];
        float dv = dtr * wdt + bdtv;
        float delta = (dv > 20.0f) ? dv : log1pf(expf(dv));
        float dA = expf(delta * Adn);
        h = dA * h + (delta * xt) * Bn;
        float p = h * Cn;
        p += __shfl_xor(p, 1, 64);
        p += __shfl_xor(p, 2, 64);
        p += __shfl_xor(p, 4, 64);
        p += __shfl_xor(p, 8, 64);
        if (n == 0) {
            float zt = zrow[(size_t)t * (2 * D_INNER)];
            float out = (p + xt * dsk) * silu_f(zt);
            yrow[(size_t)t * D_INNER] = out;
        }
    }
}

extern "C" void kernel_launch(void* const* d_in, const int* in_sizes, int n_in,
                              void* d_out, int out_size, void* d_ws, size_t ws_size,
                              hipStream_t stream) {
    const float* x      = (const float*)d_in[0];
    const float* norm_w = (const float*)d_in[1];
    const float* W_in   = (const float*)d_in[2];
    const float* conv_w = (const float*)d_in[3];
    const float* conv_b = (const float*)d_in[4];
    const float* W_x    = (const float*)d_in[5];
    const float* A_log  = (const float*)d_in[6];
    const float* D_skip = (const float*)d_in[7];
    const float* W_dt   = (const float*)d_in[8];
    const float* b_dt   = (const float*)d_in[9];
    const float* W_out  = (const float*)d_in[10];
    float* out = (float*)d_out;

    float* ws = (float*)d_ws;
    float* xn    = ws;                          // 2048*1024
    float* xz    = xn + (size_t)NROWS * D_MODEL;        // 2048*4096
    float* xconv = xz + (size_t)NROWS * 2 * D_INNER;    // 2048*2048
    float* ssm   = xconv + (size_t)NROWS * D_INNER;     // 2048*33
    float* ybuf  = ssm + (size_t)NROWS * 33;            // 2048*2048

    // 1. RMSNorm
    rmsnorm_kernel<<<NROWS, 256, 0, stream>>>(x, norm_w, xn);
    // 2. xz = xn @ W_in^T   (M=2048, N=4096, K=1024)
    {
        dim3 grid(2 * D_INNER / 64, NROWS / 64);
        gemm_nt64<<<grid, 256, 0, stream>>>(xn, W_in, xz, nullptr, NROWS, 2 * D_INNER, D_MODEL);
    }
    // 3. depthwise conv + SiLU
    conv_silu_kernel<<<(NROWS * D_INNER) / 256, 256, 0, stream>>>(xz, conv_w, conv_b, xconv);
    // 4. ssm_params = xconv @ W_x^T (N=33)
    params_kernel<<<NROWS, 256, 0, stream>>>(xconv, W_x, ssm);
    // 5. selective scan + D_skip + SiLU(z) gating
    scan_kernel<<<BATCH * (D_INNER / 16), 256, 0, stream>>>(ssm, xconv, xz, A_log, D_skip, W_dt, b_dt, ybuf);
    // 6. out = ybuf @ W_out^T + residual  (M=2048, N=1024, K=2048)
    {
        dim3 grid(D_MODEL / 64, NROWS / 64);
        gemm_nt64<<<grid, 256, 0, stream>>>(ybuf, W_out, out, x, NROWS, D_MODEL, D_INNER);
    }
}

// Round 2
// 717.847 us; speedup vs baseline: 2.2298x; 2.2298x over previous
//
#include <hip/hip_runtime.h>
#include <math.h>

#define D_MODEL 1024
#define D_STATE 16
#define D_CONV  4
#define D_INNER 2048
#define LSEQ    1024
#define BATCH   2
#define NROWS   (BATCH * LSEQ)       // 2048
#define EPSV    1e-6f

#define CHUNK   64
#define NCHUNK  (LSEQ / CHUNK)       // 16
#define SSTATE  (BATCH * D_INNER * D_STATE)   // 65536

__device__ __forceinline__ float silu_f(float x) { return x / (1.0f + expf(-x)); }
__device__ __forceinline__ float softplus_f(float x) {
    return (x > 20.0f) ? x : log1pf(expf(x));
}

// ---------------- RMSNorm: one block per row of 1024 ----------------
__global__ __launch_bounds__(256) void rmsnorm_kernel(const float* __restrict__ x,
                                                      const float* __restrict__ w,
                                                      float* __restrict__ xn) {
    int row = blockIdx.x;
    const float4* xr = (const float4*)(x + (size_t)row * D_MODEL);
    float4 v = xr[threadIdx.x];                       // 256 threads * 4 = 1024
    float s = v.x * v.x + v.y * v.y + v.z * v.z + v.w * v.w;
#pragma unroll
    for (int off = 32; off > 0; off >>= 1) s += __shfl_down(s, off, 64);
    __shared__ float wsum[4];
    int lane = threadIdx.x & 63, wv = threadIdx.x >> 6;
    if (lane == 0) wsum[wv] = s;
    __syncthreads();
    float tot = wsum[0] + wsum[1] + wsum[2] + wsum[3];
    float scale = rsqrtf(tot * (1.0f / D_MODEL) + EPSV);
    const float4* wr = (const float4*)w;
    float4 wv4 = wr[threadIdx.x];
    float4 o;
    o.x = v.x * scale * wv4.x;
    o.y = v.y * scale * wv4.y;
    o.z = v.z * scale * wv4.z;
    o.w = v.w * scale * wv4.w;
    ((float4*)(xn + (size_t)row * D_MODEL))[threadIdx.x] = o;
}

// ---------------- GEMM NT: C[m,n] = sum_k A[m,k]*B[n,k] (+resid) ----------------
__global__ __launch_bounds__(256) void gemm_nt64(const float* __restrict__ A,
                                                 const float* __restrict__ Bm,
                                                 float* __restrict__ C,
                                                 const float* __restrict__ resid,
                                                 int M, int N, int K) {
    const int BM = 64, BN = 64, BK = 32;
    __shared__ float As[BK][BM];
    __shared__ float Bs[BK][BN];
    int tid = threadIdx.x;
    int tx = tid & 15, ty = tid >> 4;
    int m0 = blockIdx.y * BM, n0 = blockIdx.x * BN;
    float acc[4][4] = {};
    for (int k0 = 0; k0 < K; k0 += BK) {
#pragma unroll
        for (int it = 0; it < 2; ++it) {
            int f = tid + it * 256;
            int row = f >> 3;          // 0..63
            int kc = (f & 7) * 4;      // 0,4,...,28
            float4 va = *(const float4*)(A + (size_t)(m0 + row) * K + k0 + kc);
            As[kc + 0][row] = va.x; As[kc + 1][row] = va.y;
            As[kc + 2][row] = va.z; As[kc + 3][row] = va.w;
            float4 vb = *(const float4*)(Bm + (size_t)(n0 + row) * K + k0 + kc);
            Bs[kc + 0][row] = vb.x; Bs[kc + 1][row] = vb.y;
            Bs[kc + 2][row] = vb.z; Bs[kc + 3][row] = vb.w;
        }
        __syncthreads();
#pragma unroll
        for (int kk = 0; kk < BK; kk++) {
            float4 a4 = *(const float4*)&As[kk][ty * 4];
            float4 b4 = *(const float4*)&Bs[kk][tx * 4];
            float a[4] = {a4.x, a4.y, a4.z, a4.w};
            float b[4] = {b4.x, b4.y, b4.z, b4.w};
#pragma unroll
            for (int i = 0; i < 4; i++)
#pragma unroll
                for (int j = 0; j < 4; j++) acc[i][j] += a[i] * b[j];
        }
        __syncthreads();
    }
#pragma unroll
    for (int i = 0; i < 4; i++) {
        int m = m0 + ty * 4 + i;
        int n = n0 + tx * 4;
        float4 o = {acc[i][0], acc[i][1], acc[i][2], acc[i][3]};
        if (resid) {
            float4 r = *(const float4*)(resid + (size_t)m * N + n);
            o.x += r.x; o.y += r.y; o.z += r.z; o.w += r.w;
        }
        *(float4*)(C + (size_t)m * N + n) = o;
    }
}

// ---------------- depthwise causal conv(4) + bias + SiLU ----------------
__global__ __launch_bounds__(256) void conv_silu_kernel(const float* __restrict__ xz,
                                                        const float* __restrict__ w,
                                                        const float* __restrict__ cb,
                                                        float* __restrict__ xc) {
    int idx = blockIdx.x * 256 + threadIdx.x;     // B*L*D_INNER
    int d = idx & (D_INNER - 1);
    int bl = idx >> 11;
    int l = bl & (LSEQ - 1);
    int bb = bl >> 10;
    float w0 = w[d * 4 + 0], w1 = w[d * 4 + 1], w2 = w[d * 4 + 2], w3 = w[d * 4 + 3];
    const float* base = xz + (size_t)(bb * LSEQ) * (2 * D_INNER) + d;
    float acc = cb[d];
    if (l >= 3) acc += w0 * base[(size_t)(l - 3) * (2 * D_INNER)];
    if (l >= 2) acc += w1 * base[(size_t)(l - 2) * (2 * D_INNER)];
    if (l >= 1) acc += w2 * base[(size_t)(l - 1) * (2 * D_INNER)];
    acc += w3 * base[(size_t)l * (2 * D_INNER)];
    xc[idx] = silu_f(acc);
}

// ---------------- ssm_params = xc @ W_x^T  (N=33) ----------------
__global__ __launch_bounds__(256) void params_kernel(const float* __restrict__ xc,
                                                     const float* __restrict__ Wx,
                                                     float* __restrict__ ssm) {
    int row = blockIdx.x;   // B*L
    __shared__ float xs[D_INNER];
    const float4* xr = (const float4*)(xc + (size_t)row * D_INNER);
#pragma unroll
    for (int it = 0; it < 2; it++) {
        int f = threadIdx.x + it * 256;
        float4 v = xr[f];
        *(float4*)&xs[f * 4] = v;
    }
    __syncthreads();
    int lane = threadIdx.x & 63;
    int wv = threadIdx.x >> 6;
    for (int n = wv; n < 2 * D_STATE + 1; n += 4) {
        const float* wrow = Wx + (size_t)n * D_INNER;
        float s = 0.0f;
        for (int k = lane; k < D_INNER; k += 64) s += xs[k] * wrow[k];
#pragma unroll
        for (int off = 32; off > 0; off >>= 1) s += __shfl_down(s, off, 64);
        if (lane == 0) ssm[(size_t)row * 33 + n] = s;
    }
}

// ============ chunked selective scan ============
// Thread layout within a block: tid = ch*16 + n  (16 channels x 16 states).
// Block handles (b, d-group of 16, chunk of 64 timesteps).

// ---- Pass A: per-chunk affine summary (P = prod dA, Q = scan from h=0) ----
__global__ __launch_bounds__(256) void scanA_kernel(const float* __restrict__ ssm,
                                                    const float* __restrict__ xc,
                                                    const float* __restrict__ A_log,
                                                    const float* __restrict__ Wdt,
                                                    const float* __restrict__ bdt,
                                                    float* __restrict__ P,
                                                    float* __restrict__ Q) {
    int c = blockIdx.x, dg = blockIdx.y, bb = blockIdx.z;
    int d0 = dg * 16;
    int tid = threadIdx.x;
    int n = tid & 15, ch = tid >> 4;
    int d = d0 + ch;

    __shared__ float s_ssm[CHUNK * 33];     // 2112 floats, contiguous copy
    __shared__ float s_x[CHUNK][16];
    __shared__ float s_dlt[CHUNK][16];

    // stage ssm tile (contiguous, 16B-aligned) and x tile
    {
        const float4* src = (const float4*)(ssm + (size_t)(bb * LSEQ + c * CHUNK) * 33);
        for (int i = tid; i < (CHUNK * 33) / 4; i += 256)
            *(float4*)&s_ssm[i * 4] = src[i];
        int t = tid >> 2, q = tid & 3;
        const float* xrow = xc + (size_t)(bb * LSEQ + c * CHUNK + t) * D_INNER + d0;
        *(float4*)&s_x[t][q * 4] = *(const float4*)(xrow + q * 4);
    }
    __syncthreads();
    // compute delta tile once per (t,d)
    {
        int t = tid >> 2, q = tid & 3;
        float dtr = s_ssm[t * 33 + 32];
#pragma unroll
        for (int j = 0; j < 4; j++) {
            int dd = q * 4 + j;
            float dv = dtr * Wdt[d0 + dd] + bdt[d0 + dd];
            s_dlt[t][dd] = softplus_f(dv);
        }
    }
    __syncthreads();

    float Adn = -expf(A_log[(size_t)d * D_STATE + n]);
    float prod = 1.0f, h = 0.0f;
#pragma unroll 4
    for (int t = 0; t < CHUNK; t++) {
        float dlt = s_dlt[t][ch];
        float Bn  = s_ssm[t * 33 + n];
        float xt  = s_x[t][ch];
        float dA  = expf(dlt * Adn);
        prod *= dA;
        h = dA * h + (dlt * xt) * Bn;
    }
    size_t idx = (size_t)c * SSTATE + ((size_t)bb * D_INNER + d) * 16 + n;
    P[idx] = prod;
    Q[idx] = h;
}

// ---- Pass B: sequential compose over chunks; writes h_start over P ----
__global__ __launch_bounds__(256) void scanB_kernel(float* __restrict__ P,
                                                    const float* __restrict__ Q) {
    int bdn = blockIdx.x * 256 + threadIdx.x;   // 0..SSTATE-1
    float H = 0.0f;
#pragma unroll
    for (int c = 0; c < NCHUNK; c++) {
        size_t idx = (size_t)c * SSTATE + bdn;
        float p = P[idx], q = Q[idx];
        P[idx] = H;               // h at chunk start
        H = p * H + q;
    }
}

// ---- Pass C: rerun chunk scan from true h_start, produce gated y ----
__global__ __launch_bounds__(256) void scanC_kernel(const float* __restrict__ ssm,
                                                    const float* __restrict__ xc,
                                                    const float* __restrict__ xz,
                                                    const float* __restrict__ A_log,
                                                    const float* __restrict__ Wdt,
                                                    const float* __restrict__ bdt,
                                                    const float* __restrict__ Hs,
                                                    const float* __restrict__ Dskip,
                                                    float* __restrict__ y) {
    int c = blockIdx.x, dg = blockIdx.y, bb = blockIdx.z;
    int d0 = dg * 16;
    int tid = threadIdx.x;
    int n = tid & 15, ch = tid >> 4;
    int d = d0 + ch;

    __shared__ float s_ssm[CHUNK * 33];
    __shared__ float s_x[CHUNK][16];
    __shared__ float s_dlt[CHUNK][16];
    __shared__ float s_y[CHUNK][16];

    {
        const float4* src = (const float4*)(ssm + (size_t)(bb * LSEQ + c * CHUNK) * 33);
        for (int i = tid; i < (CHUNK * 33) / 4; i += 256)
            *(float4*)&s_ssm[i * 4] = src[i];
        int t = tid >> 2, q = tid & 3;
        const float* xrow = xc + (size_t)(bb * LSEQ + c * CHUNK + t) * D_INNER + d0;
        *(float4*)&s_x[t][q * 4] = *(const float4*)(xrow + q * 4);
    }
    __syncthreads();
    {
        int t = tid >> 2, q = tid & 3;
        float dtr = s_ssm[t * 33 + 32];
#pragma unroll
        for (int j = 0; j < 4; j++) {
            int dd = q * 4 + j;
            float dv = dtr * Wdt[d0 + dd] + bdt[d0 + dd];
            s_dlt[t][dd] = softplus_f(dv);
        }
    }
    __syncthreads();

    float Adn = -expf(A_log[(size_t)d * D_STATE + n]);
    float h = Hs[(size_t)c * SSTATE + ((size_t)bb * D_INNER + d) * 16 + n];
#pragma unroll 4
    for (int t = 0; t < CHUNK; t++) {
        float dlt = s_dlt[t][ch];
        float Bn  = s_ssm[t * 33 + n];
        float Cn  = s_ssm[t * 33 + 16 + n];
        float xt  = s_x[t][ch];
        float dA  = expf(dlt * Adn);
        h = dA * h + (dlt * xt) * Bn;
        float p = h * Cn;
        p += __shfl_xor(p, 1, 64);
        p += __shfl_xor(p, 2, 64);
        p += __shfl_xor(p, 4, 64);
        p += __shfl_xor(p, 8, 64);
        if (n == 0) s_y[t][ch] = p;
    }
    __syncthreads();

    // fused epilogue: y = (p + x*D) * silu(z), coalesced float4
    {
        int t = tid >> 2, q = tid & 3;
        int tg = c * CHUNK + t;
        float4 yv = *(float4*)&s_y[t][q * 4];
        float4 xv = *(float4*)&s_x[t][q * 4];
        float4 dk = *(const float4*)(Dskip + d0 + q * 4);
        float4 zv = *(const float4*)(xz + (size_t)(bb * LSEQ + tg) * (2 * D_INNER) + D_INNER + d0 + q * 4);
        float4 o;
        o.x = (yv.x + xv.x * dk.x) * silu_f(zv.x);
        o.y = (yv.y + xv.y * dk.y) * silu_f(zv.y);
        o.z = (yv.z + xv.z * dk.z) * silu_f(zv.z);
        o.w = (yv.w + xv.w * dk.w) * silu_f(zv.w);
        *(float4*)(y + (size_t)(bb * LSEQ + tg) * D_INNER + d0 + q * 4) = o;
    }
}

extern "C" void kernel_launch(void* const* d_in, const int* in_sizes, int n_in,
                              void* d_out, int out_size, void* d_ws, size_t ws_size,
                              hipStream_t stream) {
    const float* x      = (const float*)d_in[0];
    const float* norm_w = (const float*)d_in[1];
    const float* W_in   = (const float*)d_in[2];
    const float* conv_w = (const float*)d_in[3];
    const float* conv_b = (const float*)d_in[4];
    const float* W_x    = (const float*)d_in[5];
    const float* A_log  = (const float*)d_in[6];
    const float* D_skip = (const float*)d_in[7];
    const float* W_dt   = (const float*)d_in[8];
    const float* b_dt   = (const float*)d_in[9];
    const float* W_out  = (const float*)d_in[10];
    float* out = (float*)d_out;

    float* ws = (float*)d_ws;
    float* xn    = ws;                                  // 2048*1024 = 2M floats
    float* xz    = xn + (size_t)NROWS * D_MODEL;        // 2048*4096
    float* xconv = xz + (size_t)NROWS * 2 * D_INNER;    // 2048*2048
    float* ssm   = xconv + (size_t)NROWS * D_INNER;     // 2048*33
    float* ybuf  = ssm + (size_t)NROWS * 33;            // 2048*2048
    // P/Q alias xn (dead after GEMM1): 2 x 1M floats = exactly xn's 2M region
    float* Pbuf = xn;                                   // NCHUNK * SSTATE = 1M
    float* Qbuf = xn + (size_t)NCHUNK * SSTATE;         // 1M

    // 1. RMSNorm
    rmsnorm_kernel<<<NROWS, 256, 0, stream>>>(x, norm_w, xn);
    // 2. xz = xn @ W_in^T   (M=2048, N=4096, K=1024)
    {
        dim3 grid(2 * D_INNER / 64, NROWS / 64);
        gemm_nt64<<<grid, 256, 0, stream>>>(xn, W_in, xz, nullptr, NROWS, 2 * D_INNER, D_MODEL);
    }
    // 3. depthwise conv + SiLU
    conv_silu_kernel<<<(NROWS * D_INNER) / 256, 256, 0, stream>>>(xz, conv_w, conv_b, xconv);
    // 4. ssm_params = xconv @ W_x^T (N=33)
    params_kernel<<<NROWS, 256, 0, stream>>>(xconv, W_x, ssm);
    // 5. chunked selective scan (3 passes) + D_skip + SiLU(z) gating
    {
        dim3 grid(NCHUNK, D_INNER / 16, BATCH);
        scanA_kernel<<<grid, 256, 0, stream>>>(ssm, xconv, A_log, W_dt, b_dt, Pbuf, Qbuf);
        scanB_kernel<<<SSTATE / 256, 256, 0, stream>>>(Pbuf, Qbuf);
        scanC_kernel<<<grid, 256, 0, stream>>>(ssm, xconv, xz, A_log, W_dt, b_dt,
                                               Pbuf, D_skip, ybuf);
    }
    // 6. out = ybuf @ W_out^T + residual  (M=2048, N=1024, K=2048)
    {
        dim3 grid(D_MODEL / 64, NROWS / 64);
        gemm_nt64<<<grid, 256, 0, stream>>>(ybuf, W_out, out, x, NROWS, D_MODEL, D_INNER);
    }
}

// Round 4
// 435.625 us; speedup vs baseline: 3.6744x; 1.6479x over previous
//
#include <hip/hip_runtime.h>
#include <math.h>

#define D_MODEL 1024
#define D_STATE 16
#define D_CONV  4
#define D_INNER 2048
#define LSEQ    1024
#define BATCH   2
#define NROWS   (BATCH * LSEQ)       // 2048
#define EPSV    1e-6f

#define CHUNK   64
#define NCHUNK  (LSEQ / CHUNK)       // 16
#define SSTATE  (BATCH * D_INNER * D_STATE)   // 65536

typedef __attribute__((ext_vector_type(8))) short bf16x8;
typedef __attribute__((ext_vector_type(4))) float f32x4;

__device__ __forceinline__ float silu_f(float x) { return x / (1.0f + expf(-x)); }
__device__ __forceinline__ float softplus_f(float x) {
    return (x > 20.0f) ? x : log1pf(expf(x));
}
__device__ __forceinline__ unsigned short f2bf(float f) {
    unsigned int u = __float_as_uint(f);
    unsigned int r = (u + 0x7FFFu + ((u >> 16) & 1u)) >> 16;
    return (unsigned short)r;
}

// ---------------- fp32 -> bf16 bulk convert (4 elems/thread) ----------------
__global__ __launch_bounds__(256) void cvt_bf16_kernel(const float* __restrict__ src,
                                                       unsigned short* __restrict__ dst) {
    int i = blockIdx.x * 256 + threadIdx.x;
    float4 v = ((const float4*)src)[i];
    ushort4 o;
    o.x = f2bf(v.x); o.y = f2bf(v.y); o.z = f2bf(v.z); o.w = f2bf(v.w);
    ((ushort4*)dst)[i] = o;
}

// ---------------- RMSNorm: one block per row of 1024, bf16 out ----------------
__global__ __launch_bounds__(256) void rmsnorm_kernel(const float* __restrict__ x,
                                                      const float* __restrict__ w,
                                                      unsigned short* __restrict__ xnb) {
    int row = blockIdx.x;
    const float4* xr = (const float4*)(x + (size_t)row * D_MODEL);
    float4 v = xr[threadIdx.x];                       // 256 threads * 4 = 1024
    float s = v.x * v.x + v.y * v.y + v.z * v.z + v.w * v.w;
#pragma unroll
    for (int off = 32; off > 0; off >>= 1) s += __shfl_down(s, off, 64);
    __shared__ float wsum[4];
    int lane = threadIdx.x & 63, wv = threadIdx.x >> 6;
    if (lane == 0) wsum[wv] = s;
    __syncthreads();
    float tot = wsum[0] + wsum[1] + wsum[2] + wsum[3];
    float scale = rsqrtf(tot * (1.0f / D_MODEL) + EPSV);
    const float4* wr = (const float4*)w;
    float4 wv4 = wr[threadIdx.x];
    ushort4 o;
    o.x = f2bf(v.x * scale * wv4.x);
    o.y = f2bf(v.y * scale * wv4.y);
    o.z = f2bf(v.z * scale * wv4.z);
    o.w = f2bf(v.w * scale * wv4.w);
    ((ushort4*)(xnb + (size_t)row * D_MODEL))[threadIdx.x] = o;
}

// ---------------- bf16 MFMA GEMM NT: C[m,n] = sum_k A[m,k]*B[n,k] (+resid) ----
// A:[M,K] bf16 row-major, B:[N,K] bf16 row-major. Tile 128x128, BK=32.
// 256 threads = 4 waves in 2x2 arrangement of 64x64 sub-tiles.
// Staging: tile row = 32 shorts = 64 B = FOUR 16B chunks -> row=c>>2, kc=(c&3)*8.
// LDS dest = As + c*8 shorts = wave base + lane*16B (contiguous in lane order),
// and (c>>2)*32 + (c&3)*8 == c*8, so [row][kc] layout is exactly chunk order.
__global__ __launch_bounds__(256) void gemm_bt_mfma(const short* __restrict__ A,
                                                    const short* __restrict__ B,
                                                    float* __restrict__ C,
                                                    const float* __restrict__ resid,
                                                    int M, int N, int K) {
    __shared__ alignas(16) short As[128 * 32];
    __shared__ alignas(16) short Bs[128 * 32];
    int tid = threadIdx.x;
    int wave = tid >> 6, lane = tid & 63;
    int wm = (wave >> 1) * 64, wn = (wave & 1) * 64;
    int m0 = blockIdx.y * 128, n0 = blockIdx.x * 128;

    f32x4 acc[4][4];
#pragma unroll
    for (int i = 0; i < 4; i++)
#pragma unroll
        for (int j = 0; j < 4; j++) acc[i][j] = (f32x4){0.f, 0.f, 0.f, 0.f};

    const short* Ab = A + (size_t)m0 * K;
    const short* Bb = B + (size_t)n0 * K;
    int qk = (lane >> 4) * 8;    // k offset within BK: 0,8,16,24
    int rr = lane & 15;

    for (int k0 = 0; k0 < K; k0 += 32) {
#pragma unroll
        for (int it = 0; it < 2; it++) {
            int c = tid + it * 256;          // 0..511 chunk id (16B chunks)
            int row = c >> 2;                // 0..127  (4 chunks per 64B row)
            int kc = (c & 3) * 8;            // 0,8,16,24
            __builtin_amdgcn_global_load_lds(
                (const __attribute__((address_space(1))) void*)(Ab + (size_t)row * K + k0 + kc),
                (__attribute__((address_space(3))) void*)(As + c * 8), 16, 0, 0);
            __builtin_amdgcn_global_load_lds(
                (const __attribute__((address_space(1))) void*)(Bb + (size_t)row * K + k0 + kc),
                (__attribute__((address_space(3))) void*)(Bs + c * 8), 16, 0, 0);
        }
        __syncthreads();

        bf16x8 af[4], bfr[4];
#pragma unroll
        for (int i = 0; i < 4; i++) {
            af[i]  = *(const bf16x8*)(As + (wm + i * 16 + rr) * 32 + qk);
            bfr[i] = *(const bf16x8*)(Bs + (wn + i * 16 + rr) * 32 + qk);
        }
#pragma unroll
        for (int i = 0; i < 4; i++)
#pragma unroll
            for (int j = 0; j < 4; j++)
                acc[i][j] = __builtin_amdgcn_mfma_f32_16x16x32_bf16(af[i], bfr[j], acc[i][j], 0, 0, 0);
        __syncthreads();
    }

    // epilogue: C/D layout col=lane&15, row=(lane>>4)*4+reg
    int q4 = (lane >> 4) * 4;
#pragma unroll
    for (int i = 0; i < 4; i++) {
#pragma unroll
        for (int j = 0; j < 4; j++) {
            int n = n0 + wn + j * 16 + rr;
#pragma unroll
            for (int v = 0; v < 4; v++) {
                int mm = m0 + wm + i * 16 + q4 + v;
                float val = acc[i][j][v];
                if (resid) val += resid[(size_t)mm * N + n];
                C[(size_t)mm * N + n] = val;
            }
        }
    }
}

// ---------------- depthwise causal conv(4) + bias + SiLU ----------------
__global__ __launch_bounds__(256) void conv_silu_kernel(const float* __restrict__ xz,
                                                        const float* __restrict__ w,
                                                        const float* __restrict__ cb,
                                                        float* __restrict__ xc) {
    int idx = blockIdx.x * 256 + threadIdx.x;     // B*L*D_INNER
    int d = idx & (D_INNER - 1);
    int bl = idx >> 11;
    int l = bl & (LSEQ - 1);
    int bb = bl >> 10;
    float w0 = w[d * 4 + 0], w1 = w[d * 4 + 1], w2 = w[d * 4 + 2], w3 = w[d * 4 + 3];
    const float* base = xz + (size_t)(bb * LSEQ) * (2 * D_INNER) + d;
    float acc = cb[d];
    if (l >= 3) acc += w0 * base[(size_t)(l - 3) * (2 * D_INNER)];
    if (l >= 2) acc += w1 * base[(size_t)(l - 2) * (2 * D_INNER)];
    if (l >= 1) acc += w2 * base[(size_t)(l - 1) * (2 * D_INNER)];
    acc += w3 * base[(size_t)l * (2 * D_INNER)];
    xc[idx] = silu_f(acc);
}

// ---------------- ssm_params = xc @ W_x^T  (N=33) ----------------
__global__ __launch_bounds__(256) void params_kernel(const float* __restrict__ xc,
                                                     const float* __restrict__ Wx,
                                                     float* __restrict__ ssm) {
    int row = blockIdx.x;   // B*L
    __shared__ float xs[D_INNER];
    const float4* xr = (const float4*)(xc + (size_t)row * D_INNER);
#pragma unroll
    for (int it = 0; it < 2; it++) {
        int f = threadIdx.x + it * 256;
        float4 v = xr[f];
        *(float4*)&xs[f * 4] = v;
    }
    __syncthreads();
    int lane = threadIdx.x & 63;
    int wv = threadIdx.x >> 6;
    for (int n = wv; n < 2 * D_STATE + 1; n += 4) {
        const float* wrow = Wx + (size_t)n * D_INNER;
        float s = 0.0f;
        for (int k = lane; k < D_INNER; k += 64) s += xs[k] * wrow[k];
#pragma unroll
        for (int off = 32; off > 0; off >>= 1) s += __shfl_down(s, off, 64);
        if (lane == 0) ssm[(size_t)row * 33 + n] = s;
    }
}

// ============ chunked selective scan ============
// ---- Pass A: per-chunk affine summary (P = prod dA, Q = scan from h=0) ----
__global__ __launch_bounds__(256) void scanA_kernel(const float* __restrict__ ssm,
                                                    const float* __restrict__ xc,
                                                    const float* __restrict__ A_log,
                                                    const float* __restrict__ Wdt,
                                                    const float* __restrict__ bdt,
                                                    float* __restrict__ P,
                                                    float* __restrict__ Q) {
    int c = blockIdx.x, dg = blockIdx.y, bb = blockIdx.z;
    int d0 = dg * 16;
    int tid = threadIdx.x;
    int n = tid & 15, ch = tid >> 4;
    int d = d0 + ch;

    __shared__ float s_ssm[CHUNK * 33];
    __shared__ float s_x[CHUNK][16];
    __shared__ float s_dlt[CHUNK][16];

    {
        const float4* src = (const float4*)(ssm + (size_t)(bb * LSEQ + c * CHUNK) * 33);
        for (int i = tid; i < (CHUNK * 33) / 4; i += 256)
            *(float4*)&s_ssm[i * 4] = src[i];
        int t = tid >> 2, q = tid & 3;
        const float* xrow = xc + (size_t)(bb * LSEQ + c * CHUNK + t) * D_INNER + d0;
        *(float4*)&s_x[t][q * 4] = *(const float4*)(xrow + q * 4);
    }
    __syncthreads();
    {
        int t = tid >> 2, q = tid & 3;
        float dtr = s_ssm[t * 33 + 32];
#pragma unroll
        for (int j = 0; j < 4; j++) {
            int dd = q * 4 + j;
            float dv = dtr * Wdt[d0 + dd] + bdt[d0 + dd];
            s_dlt[t][dd] = softplus_f(dv);
        }
    }
    __syncthreads();

    float Adn = -expf(A_log[(size_t)d * D_STATE + n]);
    float prod = 1.0f, h = 0.0f;
#pragma unroll 4
    for (int t = 0; t < CHUNK; t++) {
        float dlt = s_dlt[t][ch];
        float Bn  = s_ssm[t * 33 + n];
        float xt  = s_x[t][ch];
        float dA  = expf(dlt * Adn);
        prod *= dA;
        h = dA * h + (dlt * xt) * Bn;
    }
    size_t idx = (size_t)c * SSTATE + ((size_t)bb * D_INNER + d) * 16 + n;
    P[idx] = prod;
    Q[idx] = h;
}

// ---- Pass B: sequential compose over chunks; writes h_start over P ----
__global__ __launch_bounds__(256) void scanB_kernel(float* __restrict__ P,
                                                    const float* __restrict__ Q) {
    int bdn = blockIdx.x * 256 + threadIdx.x;   // 0..SSTATE-1
    float H = 0.0f;
#pragma unroll
    for (int c = 0; c < NCHUNK; c++) {
        size_t idx = (size_t)c * SSTATE + bdn;
        float p = P[idx], q = Q[idx];
        P[idx] = H;               // h at chunk start
        H = p * H + q;
    }
}

// ---- Pass C: rerun chunk scan from true h_start, produce gated y (bf16) ----
__global__ __launch_bounds__(256) void scanC_kernel(const float* __restrict__ ssm,
                                                    const float* __restrict__ xc,
                                                    const float* __restrict__ xz,
                                                    const float* __restrict__ A_log,
                                                    const float* __restrict__ Wdt,
                                                    const float* __restrict__ bdt,
                                                    const float* __restrict__ Hs,
                                                    const float* __restrict__ Dskip,
                                                    unsigned short* __restrict__ yb) {
    int c = blockIdx.x, dg = blockIdx.y, bb = blockIdx.z;
    int d0 = dg * 16;
    int tid = threadIdx.x;
    int n = tid & 15, ch = tid >> 4;
    int d = d0 + ch;

    __shared__ float s_ssm[CHUNK * 33];
    __shared__ float s_x[CHUNK][16];
    __shared__ float s_dlt[CHUNK][16];
    __shared__ float s_y[CHUNK][16];

    {
        const float4* src = (const float4*)(ssm + (size_t)(bb * LSEQ + c * CHUNK) * 33);
        for (int i = tid; i < (CHUNK * 33) / 4; i += 256)
            *(float4*)&s_ssm[i * 4] = src[i];
        int t = tid >> 2, q = tid & 3;
        const float* xrow = xc + (size_t)(bb * LSEQ + c * CHUNK + t) * D_INNER + d0;
        *(float4*)&s_x[t][q * 4] = *(const float4*)(xrow + q * 4);
    }
    __syncthreads();
    {
        int t = tid >> 2, q = tid & 3;
        float dtr = s_ssm[t * 33 + 32];
#pragma unroll
        for (int j = 0; j < 4; j++) {
            int dd = q * 4 + j;
            float dv = dtr * Wdt[d0 + dd] + bdt[d0 + dd];
            s_dlt[t][dd] = softplus_f(dv);
        }
    }
    __syncthreads();

    float Adn = -expf(A_log[(size_t)d * D_STATE + n]);
    float h = Hs[(size_t)c * SSTATE + ((size_t)bb * D_INNER + d) * 16 + n];
#pragma unroll 4
    for (int t = 0; t < CHUNK; t++) {
        float dlt = s_dlt[t][ch];
        float Bn  = s_ssm[t * 33 + n];
        float Cn  = s_ssm[t * 33 + 16 + n];
        float xt  = s_x[t][ch];
        float dA  = expf(dlt * Adn);
        h = dA * h + (dlt * xt) * Bn;
        float p = h * Cn;
        p += __shfl_xor(p, 1, 64);
        p += __shfl_xor(p, 2, 64);
        p += __shfl_xor(p, 4, 64);
        p += __shfl_xor(p, 8, 64);
        if (n == 0) s_y[t][ch] = p;
    }
    __syncthreads();

    // fused epilogue: y = (p + x*D) * silu(z) -> bf16, coalesced
    {
        int t = tid >> 2, q = tid & 3;
        int tg = c * CHUNK + t;
        float4 yv = *(float4*)&s_y[t][q * 4];
        float4 xv = *(float4*)&s_x[t][q * 4];
        float4 dk = *(const float4*)(Dskip + d0 + q * 4);
        float4 zv = *(const float4*)(xz + (size_t)(bb * LSEQ + tg) * (2 * D_INNER) + D_INNER + d0 + q * 4);
        ushort4 o;
        o.x = f2bf((yv.x + xv.x * dk.x) * silu_f(zv.x));
        o.y = f2bf((yv.y + xv.y * dk.y) * silu_f(zv.y));
        o.z = f2bf((yv.z + xv.z * dk.z) * silu_f(zv.z));
        o.w = f2bf((yv.w + xv.w * dk.w) * silu_f(zv.w));
        *(ushort4*)(yb + (size_t)(bb * LSEQ + tg) * D_INNER + d0 + q * 4) = o;
    }
}

extern "C" void kernel_launch(void* const* d_in, const int* in_sizes, int n_in,
                              void* d_out, int out_size, void* d_ws, size_t ws_size,
                              hipStream_t stream) {
    const float* x      = (const float*)d_in[0];
    const float* norm_w = (const float*)d_in[1];
    const float* W_in   = (const float*)d_in[2];
    const float* conv_w = (const float*)d_in[3];
    const float* conv_b = (const float*)d_in[4];
    const float* W_x    = (const float*)d_in[5];
    const float* A_log  = (const float*)d_in[6];
    const float* D_skip = (const float*)d_in[7];
    const float* W_dt   = (const float*)d_in[8];
    const float* b_dt   = (const float*)d_in[9];
    const float* W_out  = (const float*)d_in[10];
    float* out = (float*)d_out;

    // workspace layout (float-equivalent offsets; total ~18.07M floats = 72 MB)
    float* ws = (float*)d_ws;
    float* xz      = ws;                                    // 2048*4096  = 8M f
    float* xconv   = xz + (size_t)NROWS * 2 * D_INNER;      // 2048*2048  = 4M f
    float* ssm     = xconv + (size_t)NROWS * D_INNER;       // 2048*33
    float* after   = ssm + (size_t)NROWS * 33;
    unsigned short* xnb    = (unsigned short*)after;                        // 2M shorts = 1M f
    unsigned short* W_in_b = (unsigned short*)(after + 1024 * 1024);        // 4M shorts = 2M f
    unsigned short* W_out_b= (unsigned short*)(after + 3 * 1024 * 1024);    // 2M shorts = 1M f
    unsigned short* ybuf_b = (unsigned short*)(after + 4 * 1024 * 1024);    // 4M shorts = 2M f
    // P/Q alias W_in_b's region (dead after GEMM1): 2 x 1M floats
    float* Pbuf = after + 1024 * 1024;
    float* Qbuf = Pbuf + (size_t)NCHUNK * SSTATE;

    // 0. weight converts (ws is re-poisoned before every call)
    cvt_bf16_kernel<<<(2 * D_INNER * D_MODEL) / 1024, 256, 0, stream>>>(W_in, W_in_b);
    cvt_bf16_kernel<<<(D_MODEL * D_INNER) / 1024, 256, 0, stream>>>(W_out, W_out_b);
    // 1. RMSNorm -> bf16
    rmsnorm_kernel<<<NROWS, 256, 0, stream>>>(x, norm_w, xnb);
    // 2. xz = xn @ W_in^T  (M=2048, N=4096, K=1024) bf16 MFMA
    {
        dim3 grid(2 * D_INNER / 128, NROWS / 128);
        gemm_bt_mfma<<<grid, 256, 0, stream>>>((const short*)xnb, (const short*)W_in_b,
                                               xz, nullptr, NROWS, 2 * D_INNER, D_MODEL);
    }
    // 3. depthwise conv + SiLU
    conv_silu_kernel<<<(NROWS * D_INNER) / 256, 256, 0, stream>>>(xz, conv_w, conv_b, xconv);
    // 4. ssm_params = xconv @ W_x^T (N=33)
    params_kernel<<<NROWS, 256, 0, stream>>>(xconv, W_x, ssm);
    // 5. chunked selective scan (3 passes) + D_skip + SiLU(z) gating -> bf16 y
    {
        dim3 grid(NCHUNK, D_INNER / 16, BATCH);
        scanA_kernel<<<grid, 256, 0, stream>>>(ssm, xconv, A_log, W_dt, b_dt, Pbuf, Qbuf);
        scanB_kernel<<<SSTATE / 256, 256, 0, stream>>>(Pbuf, Qbuf);
        scanC_kernel<<<grid, 256, 0, stream>>>(ssm, xconv, xz, A_log, W_dt, b_dt,
                                               Pbuf, D_skip, ybuf_b);
    }
    // 6. out = y @ W_out^T + residual  (M=2048, N=1024, K=2048) bf16 MFMA
    {
        dim3 grid(D_MODEL / 128, NROWS / 128);
        gemm_bt_mfma<<<grid, 256, 0, stream>>>((const short*)ybuf_b, (const short*)W_out_b,
                                               out, x, NROWS, D_MODEL, D_INNER);
    }
}

// Round 5
// 340.892 us; speedup vs baseline: 4.6955x; 1.2779x over previous
//
#include <hip/hip_runtime.h>
#include <math.h>

#define D_MODEL 1024
#define D_STATE 16
#define D_CONV  4
#define D_INNER 2048
#define LSEQ    1024
#define BATCH   2
#define NROWS   (BATCH * LSEQ)       // 2048
#define EPSV    1e-6f

#define CHUNK   64
#define NCHUNK  (LSEQ / CHUNK)       // 16
#define SSTATE  (BATCH * D_INNER * D_STATE)   // 65536

typedef __attribute__((ext_vector_type(8))) short bf16x8;
typedef __attribute__((ext_vector_type(4))) float f32x4;

__device__ __forceinline__ float silu_f(float x) { return x / (1.0f + expf(-x)); }
__device__ __forceinline__ float softplus_f(float x) {
    return (x > 20.0f) ? x : log1pf(expf(x));
}
__device__ __forceinline__ unsigned short f2bf(float f) {
    unsigned int u = __float_as_uint(f);
    unsigned int r = (u + 0x7FFFu + ((u >> 16) & 1u)) >> 16;
    return (unsigned short)r;
}

// ---------------- fp32 -> bf16 bulk convert (4 elems/thread) ----------------
__global__ __launch_bounds__(256) void cvt_bf16_kernel(const float* __restrict__ src,
                                                       unsigned short* __restrict__ dst) {
    int i = blockIdx.x * 256 + threadIdx.x;
    float4 v = ((const float4*)src)[i];
    ushort4 o;
    o.x = f2bf(v.x); o.y = f2bf(v.y); o.z = f2bf(v.z); o.w = f2bf(v.w);
    ((ushort4*)dst)[i] = o;
}

// ---------------- RMSNorm: one block per row of 1024, bf16 out ----------------
__global__ __launch_bounds__(256) void rmsnorm_kernel(const float* __restrict__ x,
                                                      const float* __restrict__ w,
                                                      unsigned short* __restrict__ xnb) {
    int row = blockIdx.x;
    const float4* xr = (const float4*)(x + (size_t)row * D_MODEL);
    float4 v = xr[threadIdx.x];                       // 256 threads * 4 = 1024
    float s = v.x * v.x + v.y * v.y + v.z * v.z + v.w * v.w;
#pragma unroll
    for (int off = 32; off > 0; off >>= 1) s += __shfl_down(s, off, 64);
    __shared__ float wsum[4];
    int lane = threadIdx.x & 63, wv = threadIdx.x >> 6;
    if (lane == 0) wsum[wv] = s;
    __syncthreads();
    float tot = wsum[0] + wsum[1] + wsum[2] + wsum[3];
    float scale = rsqrtf(tot * (1.0f / D_MODEL) + EPSV);
    const float4* wr = (const float4*)w;
    float4 wv4 = wr[threadIdx.x];
    ushort4 o;
    o.x = f2bf(v.x * scale * wv4.x);
    o.y = f2bf(v.y * scale * wv4.y);
    o.z = f2bf(v.z * scale * wv4.z);
    o.w = f2bf(v.w * scale * wv4.w);
    ((ushort4*)(xnb + (size_t)row * D_MODEL))[threadIdx.x] = o;
}

// ---------------- bf16 MFMA GEMM NT: C[m,n] = sum_k A[m,k]*B[n,k] (+resid) ----
// A:[M,K] bf16 row-major, B:[N,K] bf16 row-major. Tile 128x128, BK=32.
// 256 threads = 4 waves in 2x2 arrangement of 64x64 sub-tiles.
// Staging: tile row = 32 shorts = 64 B = FOUR 16B chunks -> row=c>>2, kc=(c&3)*8.
__global__ __launch_bounds__(256) void gemm_bt_mfma(const short* __restrict__ A,
                                                    const short* __restrict__ B,
                                                    float* __restrict__ C,
                                                    const float* __restrict__ resid,
                                                    int M, int N, int K) {
    __shared__ alignas(16) short As[128 * 32];
    __shared__ alignas(16) short Bs[128 * 32];
    int tid = threadIdx.x;
    int wave = tid >> 6, lane = tid & 63;
    int wm = (wave >> 1) * 64, wn = (wave & 1) * 64;
    int m0 = blockIdx.y * 128, n0 = blockIdx.x * 128;

    f32x4 acc[4][4];
#pragma unroll
    for (int i = 0; i < 4; i++)
#pragma unroll
        for (int j = 0; j < 4; j++) acc[i][j] = (f32x4){0.f, 0.f, 0.f, 0.f};

    const short* Ab = A + (size_t)m0 * K;
    const short* Bb = B + (size_t)n0 * K;
    int qk = (lane >> 4) * 8;    // k offset within BK: 0,8,16,24
    int rr = lane & 15;

    for (int k0 = 0; k0 < K; k0 += 32) {
#pragma unroll
        for (int it = 0; it < 2; it++) {
            int c = tid + it * 256;          // 0..511 chunk id (16B chunks)
            int row = c >> 2;                // 0..127  (4 chunks per 64B row)
            int kc = (c & 3) * 8;            // 0,8,16,24
            __builtin_amdgcn_global_load_lds(
                (const __attribute__((address_space(1))) void*)(Ab + (size_t)row * K + k0 + kc),
                (__attribute__((address_space(3))) void*)(As + c * 8), 16, 0, 0);
            __builtin_amdgcn_global_load_lds(
                (const __attribute__((address_space(1))) void*)(Bb + (size_t)row * K + k0 + kc),
                (__attribute__((address_space(3))) void*)(Bs + c * 8), 16, 0, 0);
        }
        __syncthreads();

        bf16x8 af[4], bfr[4];
#pragma unroll
        for (int i = 0; i < 4; i++) {
            af[i]  = *(const bf16x8*)(As + (wm + i * 16 + rr) * 32 + qk);
            bfr[i] = *(const bf16x8*)(Bs + (wn + i * 16 + rr) * 32 + qk);
        }
#pragma unroll
        for (int i = 0; i < 4; i++)
#pragma unroll
            for (int j = 0; j < 4; j++)
                acc[i][j] = __builtin_amdgcn_mfma_f32_16x16x32_bf16(af[i], bfr[j], acc[i][j], 0, 0, 0);
        __syncthreads();
    }

    // epilogue: C/D layout col=lane&15, row=(lane>>4)*4+reg
    int q4 = (lane >> 4) * 4;
#pragma unroll
    for (int i = 0; i < 4; i++) {
#pragma unroll
        for (int j = 0; j < 4; j++) {
            int n = n0 + wn + j * 16 + rr;
#pragma unroll
            for (int v = 0; v < 4; v++) {
                int mm = m0 + wm + i * 16 + q4 + v;
                float val = acc[i][j][v];
                if (resid) val += resid[(size_t)mm * N + n];
                C[(size_t)mm * N + n] = val;
            }
        }
    }
}

// ---------------- depthwise causal conv(4) + bias + SiLU ----------------
__global__ __launch_bounds__(256) void conv_silu_kernel(const float* __restrict__ xz,
                                                        const float* __restrict__ w,
                                                        const float* __restrict__ cb,
                                                        float* __restrict__ xc) {
    int idx = blockIdx.x * 256 + threadIdx.x;     // B*L*D_INNER
    int d = idx & (D_INNER - 1);
    int bl = idx >> 11;
    int l = bl & (LSEQ - 1);
    int bb = bl >> 10;
    float w0 = w[d * 4 + 0], w1 = w[d * 4 + 1], w2 = w[d * 4 + 2], w3 = w[d * 4 + 3];
    const float* base = xz + (size_t)(bb * LSEQ) * (2 * D_INNER) + d;
    float acc = cb[d];
    if (l >= 3) acc += w0 * base[(size_t)(l - 3) * (2 * D_INNER)];
    if (l >= 2) acc += w1 * base[(size_t)(l - 2) * (2 * D_INNER)];
    if (l >= 1) acc += w2 * base[(size_t)(l - 1) * (2 * D_INNER)];
    acc += w3 * base[(size_t)l * (2 * D_INNER)];
    xc[idx] = silu_f(acc);
}

// ---------------- ssm_params = xc @ W_x^T  (N=33), 4 rows/block ----------------
// 512 blocks; rows staged in LDS (32 KB); wave-per-n; float4 weight loads give
// 8 independent vmem ops per n-iter (one waitcnt) + 16 fma per load; W_x is
// re-read from L2 once per 4 rows instead of once per row.
#define PR 4
__global__ __launch_bounds__(256) void params_kernel(const float* __restrict__ xc,
                                                     const float* __restrict__ Wx,
                                                     float* __restrict__ ssm) {
    int r0 = blockIdx.x * PR;
    __shared__ alignas(16) float xs[PR][D_INNER];   // 32 KB
    const float4* src = (const float4*)(xc + (size_t)r0 * D_INNER);
    for (int i = threadIdx.x; i < PR * D_INNER / 4; i += 256)
        ((float4*)xs)[i] = src[i];
    __syncthreads();
    int lane = threadIdx.x & 63, wv = threadIdx.x >> 6;
    for (int n = wv; n < 2 * D_STATE + 1; n += 4) {
        const float4* wrow = (const float4*)(Wx + (size_t)n * D_INNER);
        float s0 = 0.f, s1 = 0.f, s2 = 0.f, s3 = 0.f;
#pragma unroll
        for (int c = 0; c < D_INNER / 4 / 64; c++) {   // 8 iters
            int k = c * 64 + lane;
            float4 w  = wrow[k];
            float4 a0 = *(const float4*)&xs[0][k * 4];
            float4 a1 = *(const float4*)&xs[1][k * 4];
            float4 a2 = *(const float4*)&xs[2][k * 4];
            float4 a3 = *(const float4*)&xs[3][k * 4];
            s0 += a0.x * w.x + a0.y * w.y + a0.z * w.z + a0.w * w.w;
            s1 += a1.x * w.x + a1.y * w.y + a1.z * w.z + a1.w * w.w;
            s2 += a2.x * w.x + a2.y * w.y + a2.z * w.z + a2.w * w.w;
            s3 += a3.x * w.x + a3.y * w.y + a3.z * w.z + a3.w * w.w;
        }
#pragma unroll
        for (int off = 32; off > 0; off >>= 1) {
            s0 += __shfl_down(s0, off, 64);
            s1 += __shfl_down(s1, off, 64);
            s2 += __shfl_down(s2, off, 64);
            s3 += __shfl_down(s3, off, 64);
        }
        if (lane == 0) {
            ssm[(size_t)(r0 + 0) * 33 + n] = s0;
            ssm[(size_t)(r0 + 1) * 33 + n] = s1;
            ssm[(size_t)(r0 + 2) * 33 + n] = s2;
            ssm[(size_t)(r0 + 3) * 33 + n] = s3;
        }
    }
}

// ============ chunked selective scan ============
// ---- Pass A: per-chunk affine summary (P = prod dA, Q = scan from h=0) ----
__global__ __launch_bounds__(256) void scanA_kernel(const float* __restrict__ ssm,
                                                    const float* __restrict__ xc,
                                                    const float* __restrict__ A_log,
                                                    const float* __restrict__ Wdt,
                                                    const float* __restrict__ bdt,
                                                    float* __restrict__ P,
                                                    float* __restrict__ Q) {
    int c = blockIdx.x, dg = blockIdx.y, bb = blockIdx.z;
    int d0 = dg * 16;
    int tid = threadIdx.x;
    int n = tid & 15, ch = tid >> 4;
    int d = d0 + ch;

    __shared__ float s_ssm[CHUNK * 33];
    __shared__ float s_x[CHUNK][16];
    __shared__ float s_dlt[CHUNK][16];

    {
        const float4* src = (const float4*)(ssm + (size_t)(bb * LSEQ + c * CHUNK) * 33);
        for (int i = tid; i < (CHUNK * 33) / 4; i += 256)
            *(float4*)&s_ssm[i * 4] = src[i];
        int t = tid >> 2, q = tid & 3;
        const float* xrow = xc + (size_t)(bb * LSEQ + c * CHUNK + t) * D_INNER + d0;
        *(float4*)&s_x[t][q * 4] = *(const float4*)(xrow + q * 4);
    }
    __syncthreads();
    {
        int t = tid >> 2, q = tid & 3;
        float dtr = s_ssm[t * 33 + 32];
#pragma unroll
        for (int j = 0; j < 4; j++) {
            int dd = q * 4 + j;
            float dv = dtr * Wdt[d0 + dd] + bdt[d0 + dd];
            s_dlt[t][dd] = softplus_f(dv);
        }
    }
    __syncthreads();

    float Adn = -expf(A_log[(size_t)d * D_STATE + n]);
    float prod = 1.0f, h = 0.0f;
#pragma unroll 4
    for (int t = 0; t < CHUNK; t++) {
        float dlt = s_dlt[t][ch];
        float Bn  = s_ssm[t * 33 + n];
        float xt  = s_x[t][ch];
        float dA  = expf(dlt * Adn);
        prod *= dA;
        h = dA * h + (dlt * xt) * Bn;
    }
    size_t idx = (size_t)c * SSTATE + ((size_t)bb * D_INNER + d) * 16 + n;
    P[idx] = prod;
    Q[idx] = h;
}

// ---- Pass B: sequential compose over chunks; writes h_start over P ----
__global__ __launch_bounds__(256) void scanB_kernel(float* __restrict__ P,
                                                    const float* __restrict__ Q) {
    int bdn = blockIdx.x * 256 + threadIdx.x;   // 0..SSTATE-1
    float H = 0.0f;
#pragma unroll
    for (int c = 0; c < NCHUNK; c++) {
        size_t idx = (size_t)c * SSTATE + bdn;
        float p = P[idx], q = Q[idx];
        P[idx] = H;               // h at chunk start
        H = p * H + q;
    }
}

// ---- Pass C: rerun chunk scan from true h_start, produce gated y (bf16) ----
__global__ __launch_bounds__(256) void scanC_kernel(const float* __restrict__ ssm,
                                                    const float* __restrict__ xc,
                                                    const float* __restrict__ xz,
                                                    const float* __restrict__ A_log,
                                                    const float* __restrict__ Wdt,
                                                    const float* __restrict__ bdt,
                                                    const float* __restrict__ Hs,
                                                    const float* __restrict__ Dskip,
                                                    unsigned short* __restrict__ yb) {
    int c = blockIdx.x, dg = blockIdx.y, bb = blockIdx.z;
    int d0 = dg * 16;
    int tid = threadIdx.x;
    int n = tid & 15, ch = tid >> 4;
    int d = d0 + ch;

    __shared__ float s_ssm[CHUNK * 33];
    __shared__ float s_x[CHUNK][16];
    __shared__ float s_dlt[CHUNK][16];
    __shared__ float s_y[CHUNK][16];

    {
        const float4* src = (const float4*)(ssm + (size_t)(bb * LSEQ + c * CHUNK) * 33);
        for (int i = tid; i < (CHUNK * 33) / 4; i += 256)
            *(float4*)&s_ssm[i * 4] = src[i];
        int t = tid >> 2, q = tid & 3;
        const float* xrow = xc + (size_t)(bb * LSEQ + c * CHUNK + t) * D_INNER + d0;
        *(float4*)&s_x[t][q * 4] = *(const float4*)(xrow + q * 4);
    }
    __syncthreads();
    {
        int t = tid >> 2, q = tid & 3;
        float dtr = s_ssm[t * 33 + 32];
#pragma unroll
        for (int j = 0; j < 4; j++) {
            int dd = q * 4 + j;
            float dv = dtr * Wdt[d0 + dd] + bdt[d0 + dd];
            s_dlt[t][dd] = softplus_f(dv);
        }
    }
    __syncthreads();

    float Adn = -expf(A_log[(size_t)d * D_STATE + n]);
    float h = Hs[(size_t)c * SSTATE + ((size_t)bb * D_INNER + d) * 16 + n];
#pragma unroll 4
    for (int t = 0; t < CHUNK; t++) {
        float dlt = s_dlt[t][ch];
        float Bn  = s_ssm[t * 33 + n];
        float Cn  = s_ssm[t * 33 + 16 + n];
        float xt  = s_x[t][ch];
        float dA  = expf(dlt * Adn);
        h = dA * h + (dlt * xt) * Bn;
        float p = h * Cn;
        p += __shfl_xor(p, 1, 64);
        p += __shfl_xor(p, 2, 64);
        p += __shfl_xor(p, 4, 64);
        p += __shfl_xor(p, 8, 64);
        if (n == 0) s_y[t][ch] = p;
    }
    __syncthreads();

    // fused epilogue: y = (p + x*D) * silu(z) -> bf16, coalesced
    {
        int t = tid >> 2, q = tid & 3;
        int tg = c * CHUNK + t;
        float4 yv = *(float4*)&s_y[t][q * 4];
        float4 xv = *(float4*)&s_x[t][q * 4];
        float4 dk = *(const float4*)(Dskip + d0 + q * 4);
        float4 zv = *(const float4*)(xz + (size_t)(bb * LSEQ + tg) * (2 * D_INNER) + D_INNER + d0 + q * 4);
        ushort4 o;
        o.x = f2bf((yv.x + xv.x * dk.x) * silu_f(zv.x));
        o.y = f2bf((yv.y + xv.y * dk.y) * silu_f(zv.y));
        o.z = f2bf((yv.z + xv.z * dk.z) * silu_f(zv.z));
        o.w = f2bf((yv.w + xv.w * dk.w) * silu_f(zv.w));
        *(ushort4*)(yb + (size_t)(bb * LSEQ + tg) * D_INNER + d0 + q * 4) = o;
    }
}

extern "C" void kernel_launch(void* const* d_in, const int* in_sizes, int n_in,
                              void* d_out, int out_size, void* d_ws, size_t ws_size,
                              hipStream_t stream) {
    const float* x      = (const float*)d_in[0];
    const float* norm_w = (const float*)d_in[1];
    const float* W_in   = (const float*)d_in[2];
    const float* conv_w = (const float*)d_in[3];
    const float* conv_b = (const float*)d_in[4];
    const float* W_x    = (const float*)d_in[5];
    const float* A_log  = (const float*)d_in[6];
    const float* D_skip = (const float*)d_in[7];
    const float* W_dt   = (const float*)d_in[8];
    const float* b_dt   = (const float*)d_in[9];
    const float* W_out  = (const float*)d_in[10];
    float* out = (float*)d_out;

    // workspace layout (float-equivalent offsets; total ~18.07M floats = 72 MB)
    float* ws = (float*)d_ws;
    float* xz      = ws;                                    // 2048*4096  = 8M f
    float* xconv   = xz + (size_t)NROWS * 2 * D_INNER;      // 2048*2048  = 4M f
    float* ssm     = xconv + (size_t)NROWS * D_INNER;       // 2048*33
    float* after   = ssm + (size_t)NROWS * 33;
    unsigned short* xnb    = (unsigned short*)after;                        // 2M shorts = 1M f
    unsigned short* W_in_b = (unsigned short*)(after + 1024 * 1024);        // 4M shorts = 2M f
    unsigned short* W_out_b= (unsigned short*)(after + 3 * 1024 * 1024);    // 2M shorts = 1M f
    unsigned short* ybuf_b = (unsigned short*)(after + 4 * 1024 * 1024);    // 4M shorts = 2M f
    // P/Q alias W_in_b's region (dead after GEMM1): 2 x 1M floats
    float* Pbuf = after + 1024 * 1024;
    float* Qbuf = Pbuf + (size_t)NCHUNK * SSTATE;

    // 0. weight converts (ws is re-poisoned before every call)
    cvt_bf16_kernel<<<(2 * D_INNER * D_MODEL) / 1024, 256, 0, stream>>>(W_in, W_in_b);
    cvt_bf16_kernel<<<(D_MODEL * D_INNER) / 1024, 256, 0, stream>>>(W_out, W_out_b);
    // 1. RMSNorm -> bf16
    rmsnorm_kernel<<<NROWS, 256, 0, stream>>>(x, norm_w, xnb);
    // 2. xz = xn @ W_in^T  (M=2048, N=4096, K=1024) bf16 MFMA
    {
        dim3 grid(2 * D_INNER / 128, NROWS / 128);
        gemm_bt_mfma<<<grid, 256, 0, stream>>>((const short*)xnb, (const short*)W_in_b,
                                               xz, nullptr, NROWS, 2 * D_INNER, D_MODEL);
    }
    // 3. depthwise conv + SiLU
    conv_silu_kernel<<<(NROWS * D_INNER) / 256, 256, 0, stream>>>(xz, conv_w, conv_b, xconv);
    // 4. ssm_params = xconv @ W_x^T (N=33), 4 rows/block
    params_kernel<<<NROWS / PR, 256, 0, stream>>>(xconv, W_x, ssm);
    // 5. chunked selective scan (3 passes) + D_skip + SiLU(z) gating -> bf16 y
    {
        dim3 grid(NCHUNK, D_INNER / 16, BATCH);
        scanA_kernel<<<grid, 256, 0, stream>>>(ssm, xconv, A_log, W_dt, b_dt, Pbuf, Qbuf);
        scanB_kernel<<<SSTATE / 256, 256, 0, stream>>>(Pbuf, Qbuf);
        scanC_kernel<<<grid, 256, 0, stream>>>(ssm, xconv, xz, A_log, W_dt, b_dt,
                                               Pbuf, D_skip, ybuf_b);
    }
    // 6. out = y @ W_out^T + residual  (M=2048, N=1024, K=2048) bf16 MFMA
    {
        dim3 grid(D_MODEL / 128, NROWS / 128);
        gemm_bt_mfma<<<grid, 256, 0, stream>>>((const short*)ybuf_b, (const short*)W_out_b,
                                               out, x, NROWS, D_MODEL, D_INNER);
    }
}

// Round 6
// 285.861 us; speedup vs baseline: 5.5994x; 1.1925x over previous
//
#include <hip/hip_runtime.h>
#include <math.h>

#define D_MODEL 1024
#define D_STATE 16
#define D_CONV  4
#define D_INNER 2048
#define LSEQ    1024
#define BATCH   2
#define NROWS   (BATCH * LSEQ)       // 2048
#define EPSV    1e-6f

#define CHUNK   64
#define NCHUNK  (LSEQ / CHUNK)       // 16
#define SSTATE  (BATCH * D_INNER * D_STATE)   // 65536
#define SROW    36                   // padded ssm row (16B-aligned b128 reads)

typedef __attribute__((ext_vector_type(8))) short bf16x8;
typedef __attribute__((ext_vector_type(4))) float f32x4;

__device__ __forceinline__ float silu_f(float x) { return x / (1.0f + __expf(-x)); }
__device__ __forceinline__ float softplus_f(float x) {
    return (x > 20.0f) ? x : __logf(1.0f + __expf(x));
}
__device__ __forceinline__ unsigned short f2bf(float f) {
    unsigned int u = __float_as_uint(f);
    unsigned int r = (u + 0x7FFFu + ((u >> 16) & 1u)) >> 16;
    return (unsigned short)r;
}

// ---------------- fp32 -> bf16 bulk convert (4 elems/thread) ----------------
__global__ __launch_bounds__(256) void cvt_bf16_kernel(const float* __restrict__ src,
                                                       unsigned short* __restrict__ dst) {
    int i = blockIdx.x * 256 + threadIdx.x;
    float4 v = ((const float4*)src)[i];
    ushort4 o;
    o.x = f2bf(v.x); o.y = f2bf(v.y); o.z = f2bf(v.z); o.w = f2bf(v.w);
    ((ushort4*)dst)[i] = o;
}

// ---------------- RMSNorm: one block per row of 1024, bf16 out ----------------
__global__ __launch_bounds__(256) void rmsnorm_kernel(const float* __restrict__ x,
                                                      const float* __restrict__ w,
                                                      unsigned short* __restrict__ xnb) {
    int row = blockIdx.x;
    const float4* xr = (const float4*)(x + (size_t)row * D_MODEL);
    float4 v = xr[threadIdx.x];                       // 256 threads * 4 = 1024
    float s = v.x * v.x + v.y * v.y + v.z * v.z + v.w * v.w;
#pragma unroll
    for (int off = 32; off > 0; off >>= 1) s += __shfl_down(s, off, 64);
    __shared__ float wsum[4];
    int lane = threadIdx.x & 63, wv = threadIdx.x >> 6;
    if (lane == 0) wsum[wv] = s;
    __syncthreads();
    float tot = wsum[0] + wsum[1] + wsum[2] + wsum[3];
    float scale = rsqrtf(tot * (1.0f / D_MODEL) + EPSV);
    const float4* wr = (const float4*)w;
    float4 wv4 = wr[threadIdx.x];
    ushort4 o;
    o.x = f2bf(v.x * scale * wv4.x);
    o.y = f2bf(v.y * scale * wv4.y);
    o.z = f2bf(v.z * scale * wv4.z);
    o.w = f2bf(v.w * scale * wv4.w);
    ((ushort4*)(xnb + (size_t)row * D_MODEL))[threadIdx.x] = o;
}

// ---------------- bf16 MFMA GEMM NT: C[m,n] = sum_k A[m,k]*B[n,k] (+resid) ----
__global__ __launch_bounds__(256) void gemm_bt_mfma(const short* __restrict__ A,
                                                    const short* __restrict__ B,
                                                    float* __restrict__ C,
                                                    const float* __restrict__ resid,
                                                    int M, int N, int K) {
    __shared__ alignas(16) short As[128 * 32];
    __shared__ alignas(16) short Bs[128 * 32];
    int tid = threadIdx.x;
    int wave = tid >> 6, lane = tid & 63;
    int wm = (wave >> 1) * 64, wn = (wave & 1) * 64;
    int m0 = blockIdx.y * 128, n0 = blockIdx.x * 128;

    f32x4 acc[4][4];
#pragma unroll
    for (int i = 0; i < 4; i++)
#pragma unroll
        for (int j = 0; j < 4; j++) acc[i][j] = (f32x4){0.f, 0.f, 0.f, 0.f};

    const short* Ab = A + (size_t)m0 * K;
    const short* Bb = B + (size_t)n0 * K;
    int qk = (lane >> 4) * 8;    // k offset within BK: 0,8,16,24
    int rr = lane & 15;

    for (int k0 = 0; k0 < K; k0 += 32) {
#pragma unroll
        for (int it = 0; it < 2; it++) {
            int c = tid + it * 256;          // 0..511 chunk id (16B chunks)
            int row = c >> 2;                // 0..127  (4 chunks per 64B row)
            int kc = (c & 3) * 8;            // 0,8,16,24
            __builtin_amdgcn_global_load_lds(
                (const __attribute__((address_space(1))) void*)(Ab + (size_t)row * K + k0 + kc),
                (__attribute__((address_space(3))) void*)(As + c * 8), 16, 0, 0);
            __builtin_amdgcn_global_load_lds(
                (const __attribute__((address_space(1))) void*)(Bb + (size_t)row * K + k0 + kc),
                (__attribute__((address_space(3))) void*)(Bs + c * 8), 16, 0, 0);
        }
        __syncthreads();

        bf16x8 af[4], bfr[4];
#pragma unroll
        for (int i = 0; i < 4; i++) {
            af[i]  = *(const bf16x8*)(As + (wm + i * 16 + rr) * 32 + qk);
            bfr[i] = *(const bf16x8*)(Bs + (wn + i * 16 + rr) * 32 + qk);
        }
#pragma unroll
        for (int i = 0; i < 4; i++)
#pragma unroll
            for (int j = 0; j < 4; j++)
                acc[i][j] = __builtin_amdgcn_mfma_f32_16x16x32_bf16(af[i], bfr[j], acc[i][j], 0, 0, 0);
        __syncthreads();
    }

    int q4 = (lane >> 4) * 4;
#pragma unroll
    for (int i = 0; i < 4; i++) {
#pragma unroll
        for (int j = 0; j < 4; j++) {
            int n = n0 + wn + j * 16 + rr;
#pragma unroll
            for (int v = 0; v < 4; v++) {
                int mm = m0 + wm + i * 16 + q4 + v;
                float val = acc[i][j][v];
                if (resid) val += resid[(size_t)mm * N + n];
                C[(size_t)mm * N + n] = val;
            }
        }
    }
}

// ---------------- depthwise causal conv(4) + bias + SiLU ----------------
__global__ __launch_bounds__(256) void conv_silu_kernel(const float* __restrict__ xz,
                                                        const float* __restrict__ w,
                                                        const float* __restrict__ cb,
                                                        float* __restrict__ xc) {
    int idx = blockIdx.x * 256 + threadIdx.x;     // B*L*D_INNER
    int d = idx & (D_INNER - 1);
    int bl = idx >> 11;
    int l = bl & (LSEQ - 1);
    int bb = bl >> 10;
    float w0 = w[d * 4 + 0], w1 = w[d * 4 + 1], w2 = w[d * 4 + 2], w3 = w[d * 4 + 3];
    const float* base = xz + (size_t)(bb * LSEQ) * (2 * D_INNER) + d;
    float acc = cb[d];
    if (l >= 3) acc += w0 * base[(size_t)(l - 3) * (2 * D_INNER)];
    if (l >= 2) acc += w1 * base[(size_t)(l - 2) * (2 * D_INNER)];
    if (l >= 1) acc += w2 * base[(size_t)(l - 1) * (2 * D_INNER)];
    acc += w3 * base[(size_t)l * (2 * D_INNER)];
    xc[idx] = silu_f(acc);
}

// ---------------- ssm_params = xc @ W_x^T  (N=33), 4 rows/block ----------------
#define PR 4
__global__ __launch_bounds__(256) void params_kernel(const float* __restrict__ xc,
                                                     const float* __restrict__ Wx,
                                                     float* __restrict__ ssm) {
    int r0 = blockIdx.x * PR;
    __shared__ alignas(16) float xs[PR][D_INNER];   // 32 KB
    const float4* src = (const float4*)(xc + (size_t)r0 * D_INNER);
    for (int i = threadIdx.x; i < PR * D_INNER / 4; i += 256)
        ((float4*)xs)[i] = src[i];
    __syncthreads();
    int lane = threadIdx.x & 63, wv = threadIdx.x >> 6;
    for (int n = wv; n < 2 * D_STATE + 1; n += 4) {
        const float4* wrow = (const float4*)(Wx + (size_t)n * D_INNER);
        float s0 = 0.f, s1 = 0.f, s2 = 0.f, s3 = 0.f;
#pragma unroll
        for (int c = 0; c < D_INNER / 4 / 64; c++) {   // 8 iters
            int k = c * 64 + lane;
            float4 w  = wrow[k];
            float4 a0 = *(const float4*)&xs[0][k * 4];
            float4 a1 = *(const float4*)&xs[1][k * 4];
            float4 a2 = *(const float4*)&xs[2][k * 4];
            float4 a3 = *(const float4*)&xs[3][k * 4];
            s0 += a0.x * w.x + a0.y * w.y + a0.z * w.z + a0.w * w.w;
            s1 += a1.x * w.x + a1.y * w.y + a1.z * w.z + a1.w * w.w;
            s2 += a2.x * w.x + a2.y * w.y + a2.z * w.z + a2.w * w.w;
            s3 += a3.x * w.x + a3.y * w.y + a3.z * w.z + a3.w * w.w;
        }
#pragma unroll
        for (int off = 32; off > 0; off >>= 1) {
            s0 += __shfl_down(s0, off, 64);
            s1 += __shfl_down(s1, off, 64);
            s2 += __shfl_down(s2, off, 64);
            s3 += __shfl_down(s3, off, 64);
        }
        if (lane == 0) {
            ssm[(size_t)(r0 + 0) * 33 + n] = s0;
            ssm[(size_t)(r0 + 1) * 33 + n] = s1;
            ssm[(size_t)(r0 + 2) * 33 + n] = s2;
            ssm[(size_t)(r0 + 3) * 33 + n] = s3;
        }
    }
}

// ============ chunked selective scan, channel-per-thread ============
// Block = 256 threads = 256 channels; grid (NCHUNK, D_INNER/256, BATCH).
// All 16 states live in registers; B/C are broadcast ds_read_b128 from a
// 36-padded LDS tile (16B-aligned); x/z read coalesced from global per t.

// stage CHUNK x 33 -> CHUNK x SROW padded LDS tile
__device__ __forceinline__ void stage_ssm(const float* __restrict__ ssm,
                                          float* __restrict__ s_ssm,
                                          int bb, int c, int tid) {
    int t = tid >> 2, j = tid & 3;                 // 64 rows x 4 threads
    const float* g = ssm + (size_t)(bb * LSEQ + c * CHUNK + t) * 33;
    float* s = s_ssm + t * SROW;
    for (int col = j; col < 33; col += 4) s[col] = g[col];
}

// ---- Pass A: per-chunk summary (P = prod dA = exp(Adn*sum_dlt), Q = local h) --
__global__ __launch_bounds__(256) void scanA_kernel(const float* __restrict__ ssm,
                                                    const float* __restrict__ xc,
                                                    const float* __restrict__ A_log,
                                                    const float* __restrict__ Wdt,
                                                    const float* __restrict__ bdt,
                                                    float* __restrict__ P,
                                                    float* __restrict__ Q) {
    int c = blockIdx.x, dg = blockIdx.y, bb = blockIdx.z;
    int tid = threadIdx.x;
    int d = dg * 256 + tid;
    __shared__ alignas(16) float s_ssm[CHUNK * SROW];
    stage_ssm(ssm, s_ssm, bb, c, tid);
    __syncthreads();

    float wdt = Wdt[d], bdtv = bdt[d];
    float Adn[16];
    {
        const float4* ar = (const float4*)(A_log + (size_t)d * 16);
#pragma unroll
        for (int r = 0; r < 4; r++) {
            float4 a = ar[r];
            Adn[r * 4 + 0] = -__expf(a.x);
            Adn[r * 4 + 1] = -__expf(a.y);
            Adn[r * 4 + 2] = -__expf(a.z);
            Adn[r * 4 + 3] = -__expf(a.w);
        }
    }
    float h[16];
#pragma unroll
    for (int n = 0; n < 16; n++) h[n] = 0.f;
    float sd = 0.f;
    const float* xg = xc + ((size_t)(bb * LSEQ + c * CHUNK)) * D_INNER + d;

#pragma unroll 2
    for (int t = 0; t < CHUNK; t++) {
        float dtr = s_ssm[t * SROW + 32];
        float dlt = softplus_f(dtr * wdt + bdtv);
        float xt = xg[(size_t)t * D_INNER];
        float u = dlt * xt;
        sd += dlt;
        const float4* Bq = (const float4*)&s_ssm[t * SROW];
#pragma unroll
        for (int r = 0; r < 4; r++) {
            float4 Bv = Bq[r];
            float dA0 = __expf(dlt * Adn[r * 4 + 0]);
            float dA1 = __expf(dlt * Adn[r * 4 + 1]);
            float dA2 = __expf(dlt * Adn[r * 4 + 2]);
            float dA3 = __expf(dlt * Adn[r * 4 + 3]);
            h[r * 4 + 0] = dA0 * h[r * 4 + 0] + u * Bv.x;
            h[r * 4 + 1] = dA1 * h[r * 4 + 1] + u * Bv.y;
            h[r * 4 + 2] = dA2 * h[r * 4 + 2] + u * Bv.z;
            h[r * 4 + 3] = dA3 * h[r * 4 + 3] + u * Bv.w;
        }
    }
    size_t idx = (size_t)c * SSTATE + ((size_t)bb * D_INNER + d) * 16;
#pragma unroll
    for (int r = 0; r < 4; r++) {
        float4 pv, qv;
        pv.x = __expf(Adn[r * 4 + 0] * sd);
        pv.y = __expf(Adn[r * 4 + 1] * sd);
        pv.z = __expf(Adn[r * 4 + 2] * sd);
        pv.w = __expf(Adn[r * 4 + 3] * sd);
        qv.x = h[r * 4 + 0]; qv.y = h[r * 4 + 1];
        qv.z = h[r * 4 + 2]; qv.w = h[r * 4 + 3];
        *(float4*)(P + idx + r * 4) = pv;
        *(float4*)(Q + idx + r * 4) = qv;
    }
}

// ---- Pass B: sequential compose over chunks; writes h_start over P ----
__global__ __launch_bounds__(256) void scanB_kernel(float* __restrict__ P,
                                                    const float* __restrict__ Q) {
    int bdn = blockIdx.x * 256 + threadIdx.x;   // 0..SSTATE-1
    float H = 0.0f;
#pragma unroll
    for (int c = 0; c < NCHUNK; c++) {
        size_t idx = (size_t)c * SSTATE + bdn;
        float p = P[idx], q = Q[idx];
        P[idx] = H;               // h at chunk start
        H = p * H + q;
    }
}

// ---- Pass C: rerun chunk scan from true h_start, produce gated y (bf16) ----
__global__ __launch_bounds__(256) void scanC_kernel(const float* __restrict__ ssm,
                                                    const float* __restrict__ xc,
                                                    const float* __restrict__ xz,
                                                    const float* __restrict__ A_log,
                                                    const float* __restrict__ Wdt,
                                                    const float* __restrict__ bdt,
                                                    const float* __restrict__ Hs,
                                                    const float* __restrict__ Dskip,
                                                    unsigned short* __restrict__ yb) {
    int c = blockIdx.x, dg = blockIdx.y, bb = blockIdx.z;
    int tid = threadIdx.x;
    int d = dg * 256 + tid;
    __shared__ alignas(16) float s_ssm[CHUNK * SROW];
    stage_ssm(ssm, s_ssm, bb, c, tid);
    __syncthreads();

    float wdt = Wdt[d], bdtv = bdt[d], dsk = Dskip[d];
    float Adn[16];
    {
        const float4* ar = (const float4*)(A_log + (size_t)d * 16);
#pragma unroll
        for (int r = 0; r < 4; r++) {
            float4 a = ar[r];
            Adn[r * 4 + 0] = -__expf(a.x);
            Adn[r * 4 + 1] = -__expf(a.y);
            Adn[r * 4 + 2] = -__expf(a.z);
            Adn[r * 4 + 3] = -__expf(a.w);
        }
    }
    float h[16];
    {
        size_t idx = (size_t)c * SSTATE + ((size_t)bb * D_INNER + d) * 16;
#pragma unroll
        for (int r = 0; r < 4; r++) {
            float4 hv = *(const float4*)(Hs + idx + r * 4);
            h[r * 4 + 0] = hv.x; h[r * 4 + 1] = hv.y;
            h[r * 4 + 2] = hv.z; h[r * 4 + 3] = hv.w;
        }
    }
    const float* xg = xc + ((size_t)(bb * LSEQ + c * CHUNK)) * D_INNER + d;
    const float* zg = xz + ((size_t)(bb * LSEQ + c * CHUNK)) * (2 * D_INNER) + D_INNER + d;
    unsigned short* yg = yb + ((size_t)(bb * LSEQ + c * CHUNK)) * D_INNER + d;

#pragma unroll 2
    for (int t = 0; t < CHUNK; t++) {
        float dtr = s_ssm[t * SROW + 32];
        float dlt = softplus_f(dtr * wdt + bdtv);
        float xt = xg[(size_t)t * D_INNER];
        float zt = zg[(size_t)t * (2 * D_INNER)];
        float u = dlt * xt;
        const float4* Bq = (const float4*)&s_ssm[t * SROW];
        const float4* Cq = (const float4*)&s_ssm[t * SROW + 16];
        float y = 0.f;
#pragma unroll
        for (int r = 0; r < 4; r++) {
            float4 Bv = Bq[r];
            float4 Cv = Cq[r];
            float dA0 = __expf(dlt * Adn[r * 4 + 0]);
            float dA1 = __expf(dlt * Adn[r * 4 + 1]);
            float dA2 = __expf(dlt * Adn[r * 4 + 2]);
            float dA3 = __expf(dlt * Adn[r * 4 + 3]);
            h[r * 4 + 0] = dA0 * h[r * 4 + 0] + u * Bv.x;
            h[r * 4 + 1] = dA1 * h[r * 4 + 1] + u * Bv.y;
            h[r * 4 + 2] = dA2 * h[r * 4 + 2] + u * Bv.z;
            h[r * 4 + 3] = dA3 * h[r * 4 + 3] + u * Bv.w;
            y += h[r * 4 + 0] * Cv.x + h[r * 4 + 1] * Cv.y
               + h[r * 4 + 2] * Cv.z + h[r * 4 + 3] * Cv.w;
        }
        float o = (y + xt * dsk) * silu_f(zt);
        yg[(size_t)t * D_INNER] = f2bf(o);
    }
}

extern "C" void kernel_launch(void* const* d_in, const int* in_sizes, int n_in,
                              void* d_out, int out_size, void* d_ws, size_t ws_size,
                              hipStream_t stream) {
    const float* x      = (const float*)d_in[0];
    const float* norm_w = (const float*)d_in[1];
    const float* W_in   = (const float*)d_in[2];
    const float* conv_w = (const float*)d_in[3];
    const float* conv_b = (const float*)d_in[4];
    const float* W_x    = (const float*)d_in[5];
    const float* A_log  = (const float*)d_in[6];
    const float* D_skip = (const float*)d_in[7];
    const float* W_dt   = (const float*)d_in[8];
    const float* b_dt   = (const float*)d_in[9];
    const float* W_out  = (const float*)d_in[10];
    float* out = (float*)d_out;

    // workspace layout (float-equivalent offsets; total ~18.07M floats = 72 MB)
    float* ws = (float*)d_ws;
    float* xz      = ws;                                    // 2048*4096  = 8M f
    float* xconv   = xz + (size_t)NROWS * 2 * D_INNER;      // 2048*2048  = 4M f
    float* ssm     = xconv + (size_t)NROWS * D_INNER;       // 2048*33
    float* after   = ssm + (size_t)NROWS * 33;
    unsigned short* xnb    = (unsigned short*)after;                        // 2M shorts = 1M f
    unsigned short* W_in_b = (unsigned short*)(after + 1024 * 1024);        // 4M shorts = 2M f
    unsigned short* W_out_b= (unsigned short*)(after + 3 * 1024 * 1024);    // 2M shorts = 1M f
    unsigned short* ybuf_b = (unsigned short*)(after + 4 * 1024 * 1024);    // 4M shorts = 2M f
    // P/Q alias W_in_b's region (dead after GEMM1): 2 x 1M floats
    float* Pbuf = after + 1024 * 1024;
    float* Qbuf = Pbuf + (size_t)NCHUNK * SSTATE;

    // 0. weight converts (ws is re-poisoned before every call)
    cvt_bf16_kernel<<<(2 * D_INNER * D_MODEL) / 1024, 256, 0, stream>>>(W_in, W_in_b);
    cvt_bf16_kernel<<<(D_MODEL * D_INNER) / 1024, 256, 0, stream>>>(W_out, W_out_b);
    // 1. RMSNorm -> bf16
    rmsnorm_kernel<<<NROWS, 256, 0, stream>>>(x, norm_w, xnb);
    // 2. xz = xn @ W_in^T  (M=2048, N=4096, K=1024) bf16 MFMA
    {
        dim3 grid(2 * D_INNER / 128, NROWS / 128);
        gemm_bt_mfma<<<grid, 256, 0, stream>>>((const short*)xnb, (const short*)W_in_b,
                                               xz, nullptr, NROWS, 2 * D_INNER, D_MODEL);
    }
    // 3. depthwise conv + SiLU
    conv_silu_kernel<<<(NROWS * D_INNER) / 256, 256, 0, stream>>>(xz, conv_w, conv_b, xconv);
    // 4. ssm_params = xconv @ W_x^T (N=33), 4 rows/block
    params_kernel<<<NROWS / PR, 256, 0, stream>>>(xconv, W_x, ssm);
    // 5. chunked selective scan (3 passes) + D_skip + SiLU(z) gating -> bf16 y
    {
        dim3 grid(NCHUNK, D_INNER / 256, BATCH);
        scanA_kernel<<<grid, 256, 0, stream>>>(ssm, xconv, A_log, W_dt, b_dt, Pbuf, Qbuf);
        scanB_kernel<<<SSTATE / 256, 256, 0, stream>>>(Pbuf, Qbuf);
        scanC_kernel<<<grid, 256, 0, stream>>>(ssm, xconv, xz, A_log, W_dt, b_dt,
                                               Pbuf, D_skip, ybuf_b);
    }
    // 6. out = y @ W_out^T + residual  (M=2048, N=1024, K=2048) bf16 MFMA
    {
        dim3 grid(D_MODEL / 128, NROWS / 128);
        gemm_bt_mfma<<<grid, 256, 0, stream>>>((const short*)ybuf_b, (const short*)W_out_b,
                                               out, x, NROWS, D_MODEL, D_INNER);
    }
}

// Round 7
// 251.162 us; speedup vs baseline: 6.3729x; 1.1381x over previous
//
#include <hip/hip_runtime.h>
#include <math.h>

#define D_MODEL 1024
#define D_STATE 16
#define D_CONV  4
#define D_INNER 2048
#define LSEQ    1024
#define BATCH   2
#define NROWS   (BATCH * LSEQ)       // 2048
#define EPSV    1e-6f

#define CHUNK   64
#define NCHUNK  (LSEQ / CHUNK)       // 16
#define SSTATE  (BATCH * D_INNER * D_STATE)   // 65536
#define SROW    36                   // padded ssm row (16B-aligned b128 reads)

typedef __attribute__((ext_vector_type(8))) short bf16x8;
typedef __attribute__((ext_vector_type(4))) float f32x4;

__device__ __forceinline__ float silu_f(float x) { return x / (1.0f + __expf(-x)); }
__device__ __forceinline__ float softplus_f(float x) {
    return (x > 20.0f) ? x : __logf(1.0f + __expf(x));
}
__device__ __forceinline__ unsigned short f2bf(float f) {
    unsigned int u = __float_as_uint(f);
    unsigned int r = (u + 0x7FFFu + ((u >> 16) & 1u)) >> 16;
    return (unsigned short)r;
}

// ---------------- fp32 -> bf16 bulk convert (4 elems/thread) ----------------
__global__ __launch_bounds__(256) void cvt_bf16_kernel(const float* __restrict__ src,
                                                       unsigned short* __restrict__ dst) {
    int i = blockIdx.x * 256 + threadIdx.x;
    float4 v = ((const float4*)src)[i];
    ushort4 o;
    o.x = f2bf(v.x); o.y = f2bf(v.y); o.z = f2bf(v.z); o.w = f2bf(v.w);
    ((ushort4*)dst)[i] = o;
}

// ---------------- RMSNorm: one block per row of 1024, bf16 out ----------------
__global__ __launch_bounds__(256) void rmsnorm_kernel(const float* __restrict__ x,
                                                      const float* __restrict__ w,
                                                      unsigned short* __restrict__ xnb) {
    int row = blockIdx.x;
    const float4* xr = (const float4*)(x + (size_t)row * D_MODEL);
    float4 v = xr[threadIdx.x];                       // 256 threads * 4 = 1024
    float s = v.x * v.x + v.y * v.y + v.z * v.z + v.w * v.w;
#pragma unroll
    for (int off = 32; off > 0; off >>= 1) s += __shfl_down(s, off, 64);
    __shared__ float wsum[4];
    int lane = threadIdx.x & 63, wv = threadIdx.x >> 6;
    if (lane == 0) wsum[wv] = s;
    __syncthreads();
    float tot = wsum[0] + wsum[1] + wsum[2] + wsum[3];
    float scale = rsqrtf(tot * (1.0f / D_MODEL) + EPSV);
    const float4* wr = (const float4*)w;
    float4 wv4 = wr[threadIdx.x];
    ushort4 o;
    o.x = f2bf(v.x * scale * wv4.x);
    o.y = f2bf(v.y * scale * wv4.y);
    o.z = f2bf(v.z * scale * wv4.z);
    o.w = f2bf(v.w * scale * wv4.w);
    ((ushort4*)(xnb + (size_t)row * D_MODEL))[threadIdx.x] = o;
}

// ------- bf16 MFMA GEMM NT, tiled TMxTN, explicit double-buffered staging -----
// A:[M,K] bf16 row-major, B:[N,K] bf16 row-major, BK=32.
// 4 waves in 2x2; wave sub-tile (TM/2)x(TN/2); MI=TM/32, NJ=TN/32 MFMA grid.
// Pipeline: issue tile k+1 global_load_lds into buf^1, then s_waitcnt vmcnt(JL)
// (keeps the JL newest loads in flight -> tile k drained), raw s_barrier,
// ds_read+MFMA on buf, raw s_barrier (protects buf from next-next DMA).
// Raw barriers avoid __syncthreads' full vmcnt(0) drain (m97's ~20% stall).
template<int TM, int TN, int JL>
__global__ __launch_bounds__(256) void gemm_bt_db(const short* __restrict__ A,
                                                  const short* __restrict__ B,
                                                  float* __restrict__ C,
                                                  const float* __restrict__ resid,
                                                  int M, int N, int K) {
    constexpr int MI = TM / 32, NJ = TN / 32;
    __shared__ alignas(16) short As[2][TM * 32];
    __shared__ alignas(16) short Bs[2][TN * 32];
    int tid = threadIdx.x;
    int wave = tid >> 6, lane = tid & 63;
    int wm = (wave >> 1) * (TM / 2), wn = (wave & 1) * (TN / 2);
    int m0 = blockIdx.y * TM, n0 = blockIdx.x * TN;

    f32x4 acc[MI][NJ];
#pragma unroll
    for (int i = 0; i < MI; i++)
#pragma unroll
        for (int j = 0; j < NJ; j++) acc[i][j] = (f32x4){0.f, 0.f, 0.f, 0.f};

    const short* Ab = A + (size_t)m0 * K;
    const short* Bb = B + (size_t)n0 * K;
    int qk = (lane >> 4) * 8;    // k offset within BK: 0,8,16,24
    int rr = lane & 15;

    auto stage = [&](int k0, int buf) {
#pragma unroll
        for (int c0 = 0; c0 < TM * 4; c0 += 256) {
            int c = c0 + tid;                // 16B chunk id; row=c>>2, kc=(c&3)*8
            __builtin_amdgcn_global_load_lds(
                (const __attribute__((address_space(1))) void*)(Ab + (size_t)(c >> 2) * K + k0 + (c & 3) * 8),
                (__attribute__((address_space(3))) void*)(&As[buf][c * 8]), 16, 0, 0);
        }
#pragma unroll
        for (int c0 = 0; c0 < TN * 4; c0 += 256) {
            int c = c0 + tid;
            __builtin_amdgcn_global_load_lds(
                (const __attribute__((address_space(1))) void*)(Bb + (size_t)(c >> 2) * K + k0 + (c & 3) * 8),
                (__attribute__((address_space(3))) void*)(&Bs[buf][c * 8]), 16, 0, 0);
        }
    };

    stage(0, 0);
    int KI = K / 32;
    for (int ki = 0; ki < KI; ki++) {
        int b = ki & 1;
        if (ki + 1 < KI) {
            stage((ki + 1) * 32, b ^ 1);
            __builtin_amdgcn_s_waitcnt(0xF70 | JL);   // tile k drained; k+1 in flight
        } else {
            __builtin_amdgcn_s_waitcnt(0xF70);        // vmcnt(0), lgkm/exp don't-wait
        }
        __builtin_amdgcn_s_barrier();

        bf16x8 af[MI], bfr[NJ];
#pragma unroll
        for (int i = 0; i < MI; i++)
            af[i] = *(const bf16x8*)(&As[b][(wm + i * 16 + rr) * 32 + qk]);
#pragma unroll
        for (int j = 0; j < NJ; j++)
            bfr[j] = *(const bf16x8*)(&Bs[b][(wn + j * 16 + rr) * 32 + qk]);
#pragma unroll
        for (int i = 0; i < MI; i++)
#pragma unroll
            for (int j = 0; j < NJ; j++)
                acc[i][j] = __builtin_amdgcn_mfma_f32_16x16x32_bf16(af[i], bfr[j], acc[i][j], 0, 0, 0);
        __builtin_amdgcn_s_barrier();                 // buf free for iter ki+1's DMA
    }

    // epilogue: C/D layout col=lane&15, row=(lane>>4)*4+reg
    int q4 = (lane >> 4) * 4;
#pragma unroll
    for (int i = 0; i < MI; i++) {
#pragma unroll
        for (int j = 0; j < NJ; j++) {
            int n = n0 + wn + j * 16 + rr;
#pragma unroll
            for (int v = 0; v < 4; v++) {
                int mm = m0 + wm + i * 16 + q4 + v;
                float val = acc[i][j][v];
                if (resid) val += resid[(size_t)mm * N + n];
                C[(size_t)mm * N + n] = val;
            }
        }
    }
}

// ---------------- depthwise causal conv(4) + bias + SiLU ----------------
__global__ __launch_bounds__(256) void conv_silu_kernel(const float* __restrict__ xz,
                                                        const float* __restrict__ w,
                                                        const float* __restrict__ cb,
                                                        float* __restrict__ xc) {
    int idx = blockIdx.x * 256 + threadIdx.x;     // B*L*D_INNER
    int d = idx & (D_INNER - 1);
    int bl = idx >> 11;
    int l = bl & (LSEQ - 1);
    int bb = bl >> 10;
    float w0 = w[d * 4 + 0], w1 = w[d * 4 + 1], w2 = w[d * 4 + 2], w3 = w[d * 4 + 3];
    const float* base = xz + (size_t)(bb * LSEQ) * (2 * D_INNER) + d;
    float acc = cb[d];
    if (l >= 3) acc += w0 * base[(size_t)(l - 3) * (2 * D_INNER)];
    if (l >= 2) acc += w1 * base[(size_t)(l - 2) * (2 * D_INNER)];
    if (l >= 1) acc += w2 * base[(size_t)(l - 1) * (2 * D_INNER)];
    acc += w3 * base[(size_t)l * (2 * D_INNER)];
    xc[idx] = silu_f(acc);
}

// ---------------- ssm_params = xc @ W_x^T  (N=33), 4 rows/block ----------------
#define PR 4
__global__ __launch_bounds__(256) void params_kernel(const float* __restrict__ xc,
                                                     const float* __restrict__ Wx,
                                                     float* __restrict__ ssm) {
    int r0 = blockIdx.x * PR;
    __shared__ alignas(16) float xs[PR][D_INNER];   // 32 KB
    const float4* src = (const float4*)(xc + (size_t)r0 * D_INNER);
    for (int i = threadIdx.x; i < PR * D_INNER / 4; i += 256)
        ((float4*)xs)[i] = src[i];
    __syncthreads();
    int lane = threadIdx.x & 63, wv = threadIdx.x >> 6;
    for (int n = wv; n < 2 * D_STATE + 1; n += 4) {
        const float4* wrow = (const float4*)(Wx + (size_t)n * D_INNER);
        float s0 = 0.f, s1 = 0.f, s2 = 0.f, s3 = 0.f;
#pragma unroll
        for (int c = 0; c < D_INNER / 4 / 64; c++) {   // 8 iters
            int k = c * 64 + lane;
            float4 w  = wrow[k];
            float4 a0 = *(const float4*)&xs[0][k * 4];
            float4 a1 = *(const float4*)&xs[1][k * 4];
            float4 a2 = *(const float4*)&xs[2][k * 4];
            float4 a3 = *(const float4*)&xs[3][k * 4];
            s0 += a0.x * w.x + a0.y * w.y + a0.z * w.z + a0.w * w.w;
            s1 += a1.x * w.x + a1.y * w.y + a1.z * w.z + a1.w * w.w;
            s2 += a2.x * w.x + a2.y * w.y + a2.z * w.z + a2.w * w.w;
            s3 += a3.x * w.x + a3.y * w.y + a3.z * w.z + a3.w * w.w;
        }
#pragma unroll
        for (int off = 32; off > 0; off >>= 1) {
            s0 += __shfl_down(s0, off, 64);
            s1 += __shfl_down(s1, off, 64);
            s2 += __shfl_down(s2, off, 64);
            s3 += __shfl_down(s3, off, 64);
        }
        if (lane == 0) {
            ssm[(size_t)(r0 + 0) * 33 + n] = s0;
            ssm[(size_t)(r0 + 1) * 33 + n] = s1;
            ssm[(size_t)(r0 + 2) * 33 + n] = s2;
            ssm[(size_t)(r0 + 3) * 33 + n] = s3;
        }
    }
}

// ============ chunked selective scan, channel-per-thread ============
__device__ __forceinline__ void stage_ssm(const float* __restrict__ ssm,
                                          float* __restrict__ s_ssm,
                                          int bb, int c, int tid) {
    int t = tid >> 2, j = tid & 3;                 // 64 rows x 4 threads
    const float* g = ssm + (size_t)(bb * LSEQ + c * CHUNK + t) * 33;
    float* s = s_ssm + t * SROW;
    for (int col = j; col < 33; col += 4) s[col] = g[col];
}

// ---- Pass A: per-chunk summary (P = prod dA = exp(Adn*sum_dlt), Q = local h) --
__global__ __launch_bounds__(256) void scanA_kernel(const float* __restrict__ ssm,
                                                    const float* __restrict__ xc,
                                                    const float* __restrict__ A_log,
                                                    const float* __restrict__ Wdt,
                                                    const float* __restrict__ bdt,
                                                    float* __restrict__ P,
                                                    float* __restrict__ Q) {
    int c = blockIdx.x, dg = blockIdx.y, bb = blockIdx.z;
    int tid = threadIdx.x;
    int d = dg * 256 + tid;
    __shared__ alignas(16) float s_ssm[CHUNK * SROW];
    stage_ssm(ssm, s_ssm, bb, c, tid);
    __syncthreads();

    float wdt = Wdt[d], bdtv = bdt[d];
    float Adn[16];
    {
        const float4* ar = (const float4*)(A_log + (size_t)d * 16);
#pragma unroll
        for (int r = 0; r < 4; r++) {
            float4 a = ar[r];
            Adn[r * 4 + 0] = -__expf(a.x);
            Adn[r * 4 + 1] = -__expf(a.y);
            Adn[r * 4 + 2] = -__expf(a.z);
            Adn[r * 4 + 3] = -__expf(a.w);
        }
    }
    float h[16];
#pragma unroll
    for (int n = 0; n < 16; n++) h[n] = 0.f;
    float sd = 0.f;
    const float* xg = xc + ((size_t)(bb * LSEQ + c * CHUNK)) * D_INNER + d;

#pragma unroll 2
    for (int t = 0; t < CHUNK; t++) {
        float dtr = s_ssm[t * SROW + 32];
        float dlt = softplus_f(dtr * wdt + bdtv);
        float xt = xg[(size_t)t * D_INNER];
        float u = dlt * xt;
        sd += dlt;
        const float4* Bq = (const float4*)&s_ssm[t * SROW];
#pragma unroll
        for (int r = 0; r < 4; r++) {
            float4 Bv = Bq[r];
            float dA0 = __expf(dlt * Adn[r * 4 + 0]);
            float dA1 = __expf(dlt * Adn[r * 4 + 1]);
            float dA2 = __expf(dlt * Adn[r * 4 + 2]);
            float dA3 = __expf(dlt * Adn[r * 4 + 3]);
            h[r * 4 + 0] = dA0 * h[r * 4 + 0] + u * Bv.x;
            h[r * 4 + 1] = dA1 * h[r * 4 + 1] + u * Bv.y;
            h[r * 4 + 2] = dA2 * h[r * 4 + 2] + u * Bv.z;
            h[r * 4 + 3] = dA3 * h[r * 4 + 3] + u * Bv.w;
        }
    }
    size_t idx = (size_t)c * SSTATE + ((size_t)bb * D_INNER + d) * 16;
#pragma unroll
    for (int r = 0; r < 4; r++) {
        float4 pv, qv;
        pv.x = __expf(Adn[r * 4 + 0] * sd);
        pv.y = __expf(Adn[r * 4 + 1] * sd);
        pv.z = __expf(Adn[r * 4 + 2] * sd);
        pv.w = __expf(Adn[r * 4 + 3] * sd);
        qv.x = h[r * 4 + 0]; qv.y = h[r * 4 + 1];
        qv.z = h[r * 4 + 2]; qv.w = h[r * 4 + 3];
        *(float4*)(P + idx + r * 4) = pv;
        *(float4*)(Q + idx + r * 4) = qv;
    }
}

// ---- Pass B: sequential compose over chunks; writes h_start over P ----
__global__ __launch_bounds__(256) void scanB_kernel(float* __restrict__ P,
                                                    const float* __restrict__ Q) {
    int bdn = blockIdx.x * 256 + threadIdx.x;   // 0..SSTATE-1
    float H = 0.0f;
#pragma unroll
    for (int c = 0; c < NCHUNK; c++) {
        size_t idx = (size_t)c * SSTATE + bdn;
        float p = P[idx], q = Q[idx];
        P[idx] = H;               // h at chunk start
        H = p * H + q;
    }
}

// ---- Pass C: rerun chunk scan from true h_start, produce gated y (bf16) ----
__global__ __launch_bounds__(256) void scanC_kernel(const float* __restrict__ ssm,
                                                    const float* __restrict__ xc,
                                                    const float* __restrict__ xz,
                                                    const float* __restrict__ A_log,
                                                    const float* __restrict__ Wdt,
                                                    const float* __restrict__ bdt,
                                                    const float* __restrict__ Hs,
                                                    const float* __restrict__ Dskip,
                                                    unsigned short* __restrict__ yb) {
    int c = blockIdx.x, dg = blockIdx.y, bb = blockIdx.z;
    int tid = threadIdx.x;
    int d = dg * 256 + tid;
    __shared__ alignas(16) float s_ssm[CHUNK * SROW];
    stage_ssm(ssm, s_ssm, bb, c, tid);
    __syncthreads();

    float wdt = Wdt[d], bdtv = bdt[d], dsk = Dskip[d];
    float Adn[16];
    {
        const float4* ar = (const float4*)(A_log + (size_t)d * 16);
#pragma unroll
        for (int r = 0; r < 4; r++) {
            float4 a = ar[r];
            Adn[r * 4 + 0] = -__expf(a.x);
            Adn[r * 4 + 1] = -__expf(a.y);
            Adn[r * 4 + 2] = -__expf(a.z);
            Adn[r * 4 + 3] = -__expf(a.w);
        }
    }
    float h[16];
    {
        size_t idx = (size_t)c * SSTATE + ((size_t)bb * D_INNER + d) * 16;
#pragma unroll
        for (int r = 0; r < 4; r++) {
            float4 hv = *(const float4*)(Hs + idx + r * 4);
            h[r * 4 + 0] = hv.x; h[r * 4 + 1] = hv.y;
            h[r * 4 + 2] = hv.z; h[r * 4 + 3] = hv.w;
        }
    }
    const float* xg = xc + ((size_t)(bb * LSEQ + c * CHUNK)) * D_INNER + d;
    const float* zg = xz + ((size_t)(bb * LSEQ + c * CHUNK)) * (2 * D_INNER) + D_INNER + d;
    unsigned short* yg = yb + ((size_t)(bb * LSEQ + c * CHUNK)) * D_INNER + d;

#pragma unroll 2
    for (int t = 0; t < CHUNK; t++) {
        float dtr = s_ssm[t * SROW + 32];
        float dlt = softplus_f(dtr * wdt + bdtv);
        float xt = xg[(size_t)t * D_INNER];
        float zt = zg[(size_t)t * (2 * D_INNER)];
        float u = dlt * xt;
        const float4* Bq = (const float4*)&s_ssm[t * SROW];
        const float4* Cq = (const float4*)&s_ssm[t * SROW + 16];
        float y = 0.f;
#pragma unroll
        for (int r = 0; r < 4; r++) {
            float4 Bv = Bq[r];
            float4 Cv = Cq[r];
            float dA0 = __expf(dlt * Adn[r * 4 + 0]);
            float dA1 = __expf(dlt * Adn[r * 4 + 1]);
            float dA2 = __expf(dlt * Adn[r * 4 + 2]);
            float dA3 = __expf(dlt * Adn[r * 4 + 3]);
            h[r * 4 + 0] = dA0 * h[r * 4 + 0] + u * Bv.x;
            h[r * 4 + 1] = dA1 * h[r * 4 + 1] + u * Bv.y;
            h[r * 4 + 2] = dA2 * h[r * 4 + 2] + u * Bv.z;
            h[r * 4 + 3] = dA3 * h[r * 4 + 3] + u * Bv.w;
            y += h[r * 4 + 0] * Cv.x + h[r * 4 + 1] * Cv.y
               + h[r * 4 + 2] * Cv.z + h[r * 4 + 3] * Cv.w;
        }
        float o = (y + xt * dsk) * silu_f(zt);
        yg[(size_t)t * D_INNER] = f2bf(o);
    }
}

extern "C" void kernel_launch(void* const* d_in, const int* in_sizes, int n_in,
                              void* d_out, int out_size, void* d_ws, size_t ws_size,
                              hipStream_t stream) {
    const float* x      = (const float*)d_in[0];
    const float* norm_w = (const float*)d_in[1];
    const float* W_in   = (const float*)d_in[2];
    const float* conv_w = (const float*)d_in[3];
    const float* conv_b = (const float*)d_in[4];
    const float* W_x    = (const float*)d_in[5];
    const float* A_log  = (const float*)d_in[6];
    const float* D_skip = (const float*)d_in[7];
    const float* W_dt   = (const float*)d_in[8];
    const float* b_dt   = (const float*)d_in[9];
    const float* W_out  = (const float*)d_in[10];
    float* out = (float*)d_out;

    // workspace layout (float-equivalent offsets; total ~18.07M floats = 72 MB)
    float* ws = (float*)d_ws;
    float* xz      = ws;                                    // 2048*4096  = 8M f
    float* xconv   = xz + (size_t)NROWS * 2 * D_INNER;      // 2048*2048  = 4M f
    float* ssm     = xconv + (size_t)NROWS * D_INNER;       // 2048*33
    float* after   = ssm + (size_t)NROWS * 33;
    unsigned short* xnb    = (unsigned short*)after;                        // 2M shorts = 1M f
    unsigned short* W_in_b = (unsigned short*)(after + 1024 * 1024);        // 4M shorts = 2M f
    unsigned short* W_out_b= (unsigned short*)(after + 3 * 1024 * 1024);    // 2M shorts = 1M f
    unsigned short* ybuf_b = (unsigned short*)(after + 4 * 1024 * 1024);    // 4M shorts = 2M f
    // P/Q alias W_in_b's region (dead after GEMM1): 2 x 1M floats
    float* Pbuf = after + 1024 * 1024;
    float* Qbuf = Pbuf + (size_t)NCHUNK * SSTATE;

    // 0. weight converts (ws is re-poisoned before every call)
    cvt_bf16_kernel<<<(2 * D_INNER * D_MODEL) / 1024, 256, 0, stream>>>(W_in, W_in_b);
    cvt_bf16_kernel<<<(D_MODEL * D_INNER) / 1024, 256, 0, stream>>>(W_out, W_out_b);
    // 1. RMSNorm -> bf16
    rmsnorm_kernel<<<NROWS, 256, 0, stream>>>(x, norm_w, xnb);
    // 2. xz = xn @ W_in^T  (M=2048, N=4096, K=1024) bf16 MFMA, 64x128 tile
    {
        dim3 grid(2 * D_INNER / 128, NROWS / 64);   // (32, 32) = 1024 blocks
        gemm_bt_db<64, 128, 3><<<grid, 256, 0, stream>>>(
            (const short*)xnb, (const short*)W_in_b, xz, nullptr,
            NROWS, 2 * D_INNER, D_MODEL);
    }
    // 3. depthwise conv + SiLU
    conv_silu_kernel<<<(NROWS * D_INNER) / 256, 256, 0, stream>>>(xz, conv_w, conv_b, xconv);
    // 4. ssm_params = xconv @ W_x^T (N=33), 4 rows/block
    params_kernel<<<NROWS / PR, 256, 0, stream>>>(xconv, W_x, ssm);
    // 5. chunked selective scan (3 passes) + D_skip + SiLU(z) gating -> bf16 y
    {
        dim3 grid(NCHUNK, D_INNER / 256, BATCH);
        scanA_kernel<<<grid, 256, 0, stream>>>(ssm, xconv, A_log, W_dt, b_dt, Pbuf, Qbuf);
        scanB_kernel<<<SSTATE / 256, 256, 0, stream>>>(Pbuf, Qbuf);
        scanC_kernel<<<grid, 256, 0, stream>>>(ssm, xconv, xz, A_log, W_dt, b_dt,
                                               Pbuf, D_skip, ybuf_b);
    }
    // 6. out = y @ W_out^T + residual  (M=2048, N=1024, K=2048) bf16 MFMA, 64x64
    {
        dim3 grid(D_MODEL / 64, NROWS / 64);        // (16, 32) = 512 blocks
        gemm_bt_db<64, 64, 2><<<grid, 256, 0, stream>>>(
            (const short*)ybuf_b, (const short*)W_out_b, out, x,
            NROWS, D_MODEL, D_INNER);
    }
}